// Round 1
// baseline (3822.778 us; speedup 1.0000x reference)
//
#include <hip/hip_runtime.h>
#include <hip/hip_bf16.h>

#define D_  1024
#define H_  16
#define HD_ 64
#define L_  2048
#define B_  2
#define M_  (B_*L_)   // 4096 rows

typedef short short8 __attribute__((ext_vector_type(8)));

__device__ __forceinline__ float bf2f(short s) {
    return __uint_as_float(((unsigned int)(unsigned short)s) << 16);
}

// ---------------------------------------------------------------------------
// Kernel 1: QKV projections. Y = X @ W^T + b, written head-split.
// z=0: q->qh (f32), z=1: k->kh (f32), z=2: v->vh (bf16)
// Tiled 32x32x32, 256 threads, 2x2 outputs per thread.
// ---------------------------------------------------------------------------
__global__ __launch_bounds__(256) void proj_gemm(
    const float* __restrict__ q, const float* __restrict__ k, const float* __restrict__ v,
    const float* __restrict__ Wq, const float* __restrict__ bq,
    const float* __restrict__ Wk, const float* __restrict__ bk,
    const float* __restrict__ Wv, const float* __restrict__ bv,
    float* __restrict__ qh, float* __restrict__ kh, __hip_bfloat16* __restrict__ vh)
{
    const float* X; const float* W; const float* bias;
    const int z = blockIdx.z;
    if (z == 0)      { X = q; W = Wq; bias = bq; }
    else if (z == 1) { X = k; W = Wk; bias = bk; }
    else             { X = v; W = Wv; bias = bv; }

    __shared__ float Xs[32][33];
    __shared__ float Ws[32][33];
    const int tid = threadIdx.x;
    const int tx = tid & 15, ty = tid >> 4;
    const int m0 = blockIdx.x * 32, n0 = blockIdx.y * 32;
    float acc00 = 0.f, acc01 = 0.f, acc10 = 0.f, acc11 = 0.f;
    const int lr = tid >> 3, lc = (tid & 7) * 4;

    for (int k0 = 0; k0 < D_; k0 += 32) {
        float4 xv = *reinterpret_cast<const float4*>(X + (size_t)(m0 + lr) * D_ + k0 + lc);
        float4 wv = *reinterpret_cast<const float4*>(W + (size_t)(n0 + lr) * D_ + k0 + lc);
        Xs[lr][lc+0] = xv.x; Xs[lr][lc+1] = xv.y; Xs[lr][lc+2] = xv.z; Xs[lr][lc+3] = xv.w;
        Ws[lr][lc+0] = wv.x; Ws[lr][lc+1] = wv.y; Ws[lr][lc+2] = wv.z; Ws[lr][lc+3] = wv.w;
        __syncthreads();
        #pragma unroll
        for (int kk = 0; kk < 32; ++kk) {
            float x0 = Xs[2*ty][kk],   x1 = Xs[2*ty+1][kk];
            float w0 = Ws[2*tx][kk],   w1 = Ws[2*tx+1][kk];
            acc00 += x0 * w0; acc01 += x0 * w1;
            acc10 += x1 * w0; acc11 += x1 * w1;
        }
        __syncthreads();
    }

    #pragma unroll
    for (int i = 0; i < 2; ++i) {
        #pragma unroll
        for (int j = 0; j < 2; ++j) {
            const int m = m0 + 2*ty + i;
            const int n = n0 + 2*tx + j;
            float val = (i == 0 ? (j == 0 ? acc00 : acc01)
                                : (j == 0 ? acc10 : acc11)) + bias[n];
            const int b = m >> 11, l = m & (L_ - 1);
            const int h = n >> 6,  hd = n & 63;
            const size_t idx = (((size_t)b * H_ + h) * L_ + l) * HD_ + hd;
            if (z == 0)      qh[idx] = val;
            else if (z == 1) kh[idx] = val;
            else             vh[idx] = __float2bfloat16(val);
        }
    }
}

// ---------------------------------------------------------------------------
// Kernel 2: fused talking-heads attention, flash-style.
// Block = (b, 16 query rows), ALL 16 heads (P couples heads pre-softmax).
// Thread t = (hg = t>>4, r = t&15): hg is h for QK^T, g for mix/softmax/PV.
// ---------------------------------------------------------------------------
#define KSLAB 1028   // f32 per head slab: 16*64 + 4 pad (head stride -> 4 banks apart)
#define VSLAB 1032   // bf16 per head slab: 16*64 + 8 pad

__global__ __launch_bounds__(256) void attn_kernel(
    const float* __restrict__ qh, const float* __restrict__ kh,
    const __hip_bfloat16* __restrict__ vh, const float* __restrict__ P,
    float* __restrict__ attn_out)
{
    __shared__ __align__(16) float          Ks[16 * KSLAB];   // 65792 B
    __shared__ __align__(16) __hip_bfloat16 Vs[16 * VSLAB];   // 33024 B
    __shared__ __align__(16) float          Sraw[16 * 16 * 20]; // 25600 B, [h][r][m pad 20]
    __shared__ float Pm[16][16];

    const int tid = threadIdx.x;
    const int b  = blockIdx.y;
    const int l0 = blockIdx.x * 16;
    const int hg = tid >> 4;
    const int r  = tid & 15;

    Pm[tid >> 4][tid & 15] = P[tid];   // Pm[h][g] = P[h*16+g]

    // Q row (f32) -> registers; only this thread consumes it.
    float qreg[64];
    {
        const float* qp = qh + (((size_t)b * H_ + hg) * L_ + l0 + r) * HD_;
        #pragma unroll
        for (int i = 0; i < 16; ++i) {
            float4 v4 = *reinterpret_cast<const float4*>(qp + i * 4);
            qreg[i*4+0] = v4.x; qreg[i*4+1] = v4.y; qreg[i*4+2] = v4.z; qreg[i*4+3] = v4.w;
        }
    }
    float acc[64];
    #pragma unroll
    for (int i = 0; i < 64; ++i) acc[i] = 0.f;
    float mrun = -1e30f, srun = 0.f;

    for (int mt = 0; mt < L_ / 16; ++mt) {
        const int m0 = mt * 16;
        // --- stage K (f32): 16 heads x 1024 f32 contiguous; 4096 float4 chunks
        #pragma unroll
        for (int i = 0; i < 16; ++i) {
            const int chunk = i * 256 + tid;
            const int h = chunk >> 8;
            const int off = chunk & 255;
            float4 kv = *reinterpret_cast<const float4*>(
                kh + (((size_t)b * H_ + h) * L_ + m0) * HD_ + off * 4);
            *reinterpret_cast<float4*>(&Ks[h * KSLAB + off * 4]) = kv;
        }
        // --- stage V (bf16): 2048 chunks of 8
        #pragma unroll
        for (int i = 0; i < 8; ++i) {
            const int chunk = i * 256 + tid;
            const int h = chunk >> 7;
            const int off = chunk & 127;
            short8 vv = *reinterpret_cast<const short8*>(
                vh + (((size_t)b * H_ + h) * L_ + m0) * HD_ + off * 8);
            *reinterpret_cast<short8*>(&Vs[h * VSLAB + off * 8]) = vv;
        }
        __syncthreads();

        // --- QK^T: thread (h=hg, r) computes 16 dots of length 64
        {
            const float* krow = &Ks[hg * KSLAB];
            float sd[16];
            #pragma unroll
            for (int m = 0; m < 16; ++m) {
                float d = 0.f;
                #pragma unroll
                for (int i = 0; i < 16; ++i) {
                    float4 k4 = *reinterpret_cast<const float4*>(krow + m * 64 + i * 4);
                    d += qreg[i*4+0]*k4.x + qreg[i*4+1]*k4.y
                       + qreg[i*4+2]*k4.z + qreg[i*4+3]*k4.w;
                }
                sd[m] = d;
            }
            float4* sp = reinterpret_cast<float4*>(&Sraw[(hg * 16 + r) * 20]);
            sp[0] = make_float4(sd[0],  sd[1],  sd[2],  sd[3]);
            sp[1] = make_float4(sd[4],  sd[5],  sd[6],  sd[7]);
            sp[2] = make_float4(sd[8],  sd[9],  sd[10], sd[11]);
            sp[3] = make_float4(sd[12], sd[13], sd[14], sd[15]);
        }
        __syncthreads();

        // --- talking-heads mix (thread (g=hg, r)): smix[m] = sum_h Sraw[h][r][m]*P[h][g]
        float smix[16];
        #pragma unroll
        for (int m = 0; m < 16; ++m) smix[m] = 0.f;
        #pragma unroll
        for (int h = 0; h < 16; ++h) {
            const float p = Pm[h][hg];
            const float4* srp = reinterpret_cast<const float4*>(&Sraw[(h * 16 + r) * 20]);
            float4 s0 = srp[0], s1 = srp[1], s2 = srp[2], s3 = srp[3];
            smix[0]  += p * s0.x; smix[1]  += p * s0.y; smix[2]  += p * s0.z; smix[3]  += p * s0.w;
            smix[4]  += p * s1.x; smix[5]  += p * s1.y; smix[6]  += p * s1.z; smix[7]  += p * s1.w;
            smix[8]  += p * s2.x; smix[9]  += p * s2.y; smix[10] += p * s2.z; smix[11] += p * s2.w;
            smix[12] += p * s3.x; smix[13] += p * s3.y; smix[14] += p * s3.z; smix[15] += p * s3.w;
        }
        // --- online softmax (scale 1/sqrt(64) folded in post-mix; linear so equivalent)
        float tmax = -1e30f;
        #pragma unroll
        for (int m = 0; m < 16; ++m) { smix[m] *= 0.125f; tmax = fmaxf(tmax, smix[m]); }
        const float mnew = fmaxf(mrun, tmax);
        const float corr = __expf(mrun - mnew);
        float pbuf[16]; float psum = 0.f;
        #pragma unroll
        for (int m = 0; m < 16; ++m) { pbuf[m] = __expf(smix[m] - mnew); psum += pbuf[m]; }
        srun = srun * corr + psum;
        #pragma unroll
        for (int i = 0; i < 64; ++i) acc[i] *= corr;
        // --- PV: acc[d] += sum_m p[m] * V[g][m][d]
        const __hip_bfloat16* vrow = &Vs[hg * VSLAB];
        #pragma unroll
        for (int m = 0; m < 16; ++m) {
            const float pm = pbuf[m];
            #pragma unroll
            for (int i = 0; i < 8; ++i) {
                short8 v8 = *reinterpret_cast<const short8*>(vrow + m * 64 + i * 8);
                #pragma unroll
                for (int j = 0; j < 8; ++j) acc[i*8+j] += pm * bf2f(v8[j]);
            }
        }
        mrun = mnew;
        __syncthreads();
    }

    // epilogue: merged [B,L,D] layout, d = g*64 + hd
    const float inv = 1.0f / srun;
    float* op = attn_out + ((size_t)(b * L_ + l0 + r)) * D_ + hg * HD_;
    #pragma unroll
    for (int i = 0; i < 16; ++i) {
        float4 o4 = make_float4(acc[i*4+0]*inv, acc[i*4+1]*inv, acc[i*4+2]*inv, acc[i*4+3]*inv);
        *reinterpret_cast<float4*>(op + i * 4) = o4;
    }
}

// ---------------------------------------------------------------------------
// Kernel 3: output projection. out = A @ Wo^T + bo  (plain [M,D] f32)
// ---------------------------------------------------------------------------
__global__ __launch_bounds__(256) void out_gemm(
    const float* __restrict__ A, const float* __restrict__ Wo,
    const float* __restrict__ bo, float* __restrict__ out)
{
    __shared__ float Xs[32][33];
    __shared__ float Ws[32][33];
    const int tid = threadIdx.x;
    const int tx = tid & 15, ty = tid >> 4;
    const int m0 = blockIdx.x * 32, n0 = blockIdx.y * 32;
    float acc00 = 0.f, acc01 = 0.f, acc10 = 0.f, acc11 = 0.f;
    const int lr = tid >> 3, lc = (tid & 7) * 4;

    for (int k0 = 0; k0 < D_; k0 += 32) {
        float4 xv = *reinterpret_cast<const float4*>(A  + (size_t)(m0 + lr) * D_ + k0 + lc);
        float4 wv = *reinterpret_cast<const float4*>(Wo + (size_t)(n0 + lr) * D_ + k0 + lc);
        Xs[lr][lc+0] = xv.x; Xs[lr][lc+1] = xv.y; Xs[lr][lc+2] = xv.z; Xs[lr][lc+3] = xv.w;
        Ws[lr][lc+0] = wv.x; Ws[lr][lc+1] = wv.y; Ws[lr][lc+2] = wv.z; Ws[lr][lc+3] = wv.w;
        __syncthreads();
        #pragma unroll
        for (int kk = 0; kk < 32; ++kk) {
            float x0 = Xs[2*ty][kk], x1 = Xs[2*ty+1][kk];
            float w0 = Ws[2*tx][kk], w1 = Ws[2*tx+1][kk];
            acc00 += x0 * w0; acc01 += x0 * w1;
            acc10 += x1 * w0; acc11 += x1 * w1;
        }
        __syncthreads();
    }
    #pragma unroll
    for (int i = 0; i < 2; ++i) {
        #pragma unroll
        for (int j = 0; j < 2; ++j) {
            const int m = m0 + 2*ty + i;
            const int n = n0 + 2*tx + j;
            float val = (i == 0 ? (j == 0 ? acc00 : acc01)
                                : (j == 0 ? acc10 : acc11)) + bo[n];
            out[(size_t)m * D_ + n] = val;
        }
    }
}

// ---------------------------------------------------------------------------
extern "C" void kernel_launch(void* const* d_in, const int* in_sizes, int n_in,
                              void* d_out, int out_size, void* d_ws, size_t ws_size,
                              hipStream_t stream) {
    const float* q  = (const float*)d_in[0];
    const float* k  = (const float*)d_in[1];
    const float* v  = (const float*)d_in[2];
    const float* Wq = (const float*)d_in[3];
    const float* bq = (const float*)d_in[4];
    const float* Wk = (const float*)d_in[5];
    const float* bk = (const float*)d_in[6];
    const float* Wv = (const float*)d_in[7];
    const float* bv = (const float*)d_in[8];
    const float* Wo = (const float*)d_in[9];
    const float* bo = (const float*)d_in[10];
    const float* P  = (const float*)d_in[11];
    float* out = (float*)d_out;

    // workspace layout (bytes):
    //   qh  f32 [B,H,L,HD]  : 16,777,216
    //   kh  f32 [B,H,L,HD]  : 16,777,216
    //   vh  bf16 [B,H,L,HD] :  8,388,608
    //   attn f32 [B,L,D]    : 16,777,216   (total 58,720,256)
    char* ws = (char*)d_ws;
    float*          qh   = (float*)(ws);
    float*          kh   = (float*)(ws + 16777216);
    __hip_bfloat16* vh   = (__hip_bfloat16*)(ws + 33554432);
    float*          attn = (float*)(ws + 41943040);

    proj_gemm<<<dim3(M_/32, D_/32, 3), 256, 0, stream>>>(
        q, k, v, Wq, bq, Wk, bk, Wv, bv, qh, kh, vh);
    attn_kernel<<<dim3(L_/16, B_), 256, 0, stream>>>(qh, kh, vh, P, attn);
    out_gemm<<<dim3(M_/32, D_/32), 256, 0, stream>>>(attn, Wo, bo, out);
}

// Round 2
// 703.870 us; speedup vs baseline: 5.4311x; 5.4311x over previous
//
#include <hip/hip_runtime.h>

#define D_  1024
#define H_  16
#define HD_ 64
#define L_  2048
#define B_  2
#define M_  (B_*L_)   // 4096 rows

typedef float f32x4  __attribute__((ext_vector_type(4)));
typedef short bf16x4 __attribute__((ext_vector_type(4)));
typedef short bf16x8 __attribute__((ext_vector_type(8)));

__device__ __forceinline__ float bf2f(short s) {
    return __uint_as_float(((unsigned int)(unsigned short)s) << 16);
}
__device__ __forceinline__ short f2bf(float f) {   // RNE
    unsigned u = __float_as_uint(f);
    unsigned r = (u + 0x7FFFu + ((u >> 16) & 1u)) >> 16;
    return (short)r;
}

// ---------------------------------------------------------------------------
// Kernel 1: QKV projections via bf16 MFMA. 128x128 tile, K-step 32, 256 thr.
// z=0: q -> qh(hi)+qlo  [b][h][l][64]      (D[n][l] orientation)
// z=1: k -> kh          [b][h][l][64]      (D[n][l])
// z=2: v -> vht         [b][h][64][L]      (D[l][n] orientation, transposed)
// ---------------------------------------------------------------------------
__global__ __launch_bounds__(256) void proj_mfma(
    const float* __restrict__ q, const float* __restrict__ k, const float* __restrict__ v,
    const float* __restrict__ Wq, const float* __restrict__ bq,
    const float* __restrict__ Wk, const float* __restrict__ bk,
    const float* __restrict__ Wv, const float* __restrict__ bv,
    short* __restrict__ qh, short* __restrict__ qlo,
    short* __restrict__ kh, short* __restrict__ vht)
{
    const int z = blockIdx.z;
    const float* X    = (z == 0) ? q  : (z == 1) ? k  : v;
    const float* W    = (z == 0) ? Wq : (z == 1) ? Wk : Wv;
    const float* bias = (z == 0) ? bq : (z == 1) ? bk : bv;

    __shared__ short Ws[128][40];   // +8 pad: 80B rows -> 16B aligned, ~2-way banks
    __shared__ short Xs[128][40];

    const int tid  = threadIdx.x;
    const int w    = tid >> 6, lane = tid & 63;
    const int l16  = lane & 15, qq = lane >> 4;
    const int m0   = blockIdx.x * 128;   // X rows (b*l)
    const int n0   = blockIdx.y * 128;   // W rows (output feature)
    const int ar0  = 64 * (w & 1);
    const int br0  = 64 * (w >> 1);

    f32x4 acc[4][4] = {};

    for (int k0 = 0; k0 < D_; k0 += 32) {
        #pragma unroll
        for (int i = 0; i < 4; ++i) {
            int fidx = i * 256 + tid;         // 1024 float4 chunks per matrix
            int r = fidx >> 3, c = fidx & 7;
            float4 wv4 = *(const float4*)(W + (size_t)(n0 + r) * D_ + k0 + c * 4);
            float4 xv4 = *(const float4*)(X + (size_t)(m0 + r) * D_ + k0 + c * 4);
            bf16x4 wb = { f2bf(wv4.x), f2bf(wv4.y), f2bf(wv4.z), f2bf(wv4.w) };
            bf16x4 xb = { f2bf(xv4.x), f2bf(xv4.y), f2bf(xv4.z), f2bf(xv4.w) };
            *(bf16x4*)&Ws[r][c * 4] = wb;
            *(bf16x4*)&Xs[r][c * 4] = xb;
        }
        __syncthreads();
        bf16x8 af[4], bf[4];
        #pragma unroll
        for (int i = 0; i < 4; ++i) {
            const short* Ab = (z < 2) ? &Ws[ar0 + 16 * i + l16][qq * 8]
                                      : &Xs[ar0 + 16 * i + l16][qq * 8];
            const short* Bb = (z < 2) ? &Xs[br0 + 16 * i + l16][qq * 8]
                                      : &Ws[br0 + 16 * i + l16][qq * 8];
            af[i] = *(const bf16x8*)Ab;
            bf[i] = *(const bf16x8*)Bb;
        }
        #pragma unroll
        for (int i = 0; i < 4; ++i)
            #pragma unroll
            for (int j = 0; j < 4; ++j)
                acc[i][j] = __builtin_amdgcn_mfma_f32_16x16x32_bf16(af[i], bf[j], acc[i][j], 0, 0, 0);
        __syncthreads();
    }

    if (z < 2) {
        // D[n][l]: rows n = n0+ar0+16i+4qq+r ; cols m = m0+br0+16j+l16
        #pragma unroll
        for (int i = 0; i < 4; ++i) {
            int nb = n0 + ar0 + 16 * i + qq * 4;
            float4 b4 = *(const float4*)(bias + nb);
            int h = nb >> 6, hd = nb & 63;
            #pragma unroll
            for (int j = 0; j < 4; ++j) {
                int m = m0 + br0 + 16 * j + l16;
                int bb = m >> 11, l = m & (L_ - 1);
                size_t o = ((((size_t)bb * H_ + h) * L_) + l) * HD_ + hd;
                f32x4 c = acc[i][j];
                float v0 = c[0] + b4.x, v1 = c[1] + b4.y, v2 = c[2] + b4.z, v3 = c[3] + b4.w;
                bf16x4 hi = { f2bf(v0), f2bf(v1), f2bf(v2), f2bf(v3) };
                if (z == 0) {
                    *(bf16x4*)&qh[o] = hi;
                    bf16x4 lo = { f2bf(v0 - bf2f(hi[0])), f2bf(v1 - bf2f(hi[1])),
                                  f2bf(v2 - bf2f(hi[2])), f2bf(v3 - bf2f(hi[3])) };
                    *(bf16x4*)&qlo[o] = lo;
                } else {
                    *(bf16x4*)&kh[o] = hi;
                }
            }
        }
    } else {
        // D[l][n]: rows m = m0+ar0+16i+4qq+r ; cols n = n0+br0+16j+l16
        #pragma unroll
        for (int i = 0; i < 4; ++i) {
            int mb = m0 + ar0 + 16 * i + qq * 4;
            int bb = mb >> 11, lb = mb & (L_ - 1);
            #pragma unroll
            for (int j = 0; j < 4; ++j) {
                int n = n0 + br0 + 16 * j + l16;
                int h = n >> 6, hd = n & 63;
                float bn = bias[n];
                size_t o = (((size_t)bb * H_ + h) * HD_ + hd) * (size_t)L_ + lb;
                f32x4 c = acc[i][j];
                bf16x4 ov = { f2bf(c[0] + bn), f2bf(c[1] + bn), f2bf(c[2] + bn), f2bf(c[3] + bn) };
                *(bf16x4*)&vht[o] = ov;
            }
        }
    }
}

// ---------------------------------------------------------------------------
// Kernel 2: fused talking-heads attention, MFMA. 512 thr (8 waves), Q-tile 16,
// KV-tile 16, all 16 heads per block. Wave w: heads/g {2w,2w+1}.
// ---------------------------------------------------------------------------
__global__ __launch_bounds__(512, 2) void attn_mfma(
    const short* __restrict__ qh, const short* __restrict__ qlo,
    const short* __restrict__ kh, const short* __restrict__ vht,
    const float* __restrict__ P, short* __restrict__ attn_out)
{
    __shared__ short Ks[16 * 16 * 64];      // [h][m][64] chunk-XOR swizzled, 32KB
    __shared__ short Vts[16 * 64 * 20];     // [h][d][16+4pad], 40KB
    __shared__ float Sraw[16 * 16 * 20];    // [h][l][16+4pad] f32, 20.5KB
    __shared__ float Smix[16 * 16 * 20];    // [g][l][16+4pad]
    __shared__ short Plds[16 * 16 * 20];    // [g][l][16+4pad] bf16, 10.2KB
    __shared__ float Pm[16][17];            // P[h][g] * 0.125

    const int tid  = threadIdx.x;
    const int b    = blockIdx.y;
    const int l0   = blockIdx.x * 16;
    const int w    = tid >> 6, lane = tid & 63;
    const int l16  = lane & 15, qq = lane >> 4;
    const int i2   = qq & 1;                 // softmax row: g = 2w + i2, l = l16

    if (tid < 256) Pm[tid >> 4][tid & 15] = P[tid] * 0.125f;

    // Preload Q fragments (hi + lo) for heads 2w, 2w+1 (both K=32 chunks)
    bf16x8 qf[2][2][2];
    #pragma unroll
    for (int hh = 0; hh < 2; ++hh)
        #pragma unroll
        for (int kc = 0; kc < 2; ++kc) {
            size_t off = (((size_t)b * H_ + 2 * w + hh) * L_ + l0 + l16) * HD_ + kc * 32 + qq * 8;
            qf[hh][kc][0] = *(const bf16x8*)(qh + off);
            qf[hh][kc][1] = *(const bf16x8*)(qlo + off);
        }

    f32x4 acc[2][4] = {};
    float mrun = -1e30f, srun = 0.f, corr = 1.f;

    for (int mt = 0; mt < L_ / 16; ++mt) {
        const int m0 = mt * 16;
        // --- stage K tile: 256 rows (h,m) x 64 bf16; thread = half-row
        {
            int row = tid >> 1, half = tid & 1;
            int h = row >> 4, m = row & 15;
            const short* src = kh + (((size_t)b * H_ + h) * L_ + m0 + m) * HD_ + half * 32;
            short* dstb = &Ks[(h * 16 + m) * 64];
            #pragma unroll
            for (int c = 0; c < 4; ++c) {
                int cg = half * 4 + c;
                bf16x8 vv = *(const bf16x8*)(src + c * 8);
                *(bf16x8*)&dstb[(cg ^ (m & 7)) * 8] = vv;
            }
        }
        // --- stage V tile: 1024 rows (h,d) x 16 bf16; thread = 2 rows
        #pragma unroll
        for (int i = 0; i < 2; ++i) {
            int row = i * 512 + tid;
            int h = row >> 6, d = row & 63;
            const short* src = vht + (((size_t)b * H_ + h) * HD_ + d) * (size_t)L_ + m0;
            short* dst = &Vts[(h * 64 + d) * 20];
            #pragma unroll
            for (int c = 0; c < 4; ++c)
                *(bf16x4*)&dst[c * 4] = *(const bf16x4*)(src + c * 4);
        }
        __syncthreads();

        // --- QK^T: D[m][l] per head; A = K rows m, B = Q cols l
        #pragma unroll
        for (int hh = 0; hh < 2; ++hh) {
            int h = 2 * w + hh;
            f32x4 s = {0.f, 0.f, 0.f, 0.f};
            #pragma unroll
            for (int kc = 0; kc < 2; ++kc) {
                bf16x8 af = *(const bf16x8*)&Ks[(h * 16 + l16) * 64 + ((4 * kc + qq) ^ (l16 & 7)) * 8];
                s = __builtin_amdgcn_mfma_f32_16x16x32_bf16(af, qf[hh][kc][0], s, 0, 0, 0);
                s = __builtin_amdgcn_mfma_f32_16x16x32_bf16(af, qf[hh][kc][1], s, 0, 0, 0);
            }
            *(f32x4*)&Sraw[(h * 16 + l16) * 20 + qq * 4] = s;   // [h][l][m: 4qq+r]
        }
        __syncthreads();

        // --- talking-heads mix: thread = (l, m, g-half); 8 g each
        {
            int l = tid & 15, m = (tid >> 4) & 15, gh = tid >> 8;
            float sr[16];
            #pragma unroll
            for (int h = 0; h < 16; ++h) sr[h] = Sraw[(h * 16 + l) * 20 + m];
            #pragma unroll
            for (int gi = 0; gi < 8; ++gi) {
                int g = gh * 8 + gi;
                float sv = 0.f;
                #pragma unroll
                for (int h = 0; h < 16; ++h) sv += Pm[h][g] * sr[h];
                Smix[(g * 16 + l) * 20 + m] = sv;
            }
        }
        __syncthreads();

        // --- online softmax, row (g = 2w + i2, l = l16); lanes 32-63 duplicate
        {
            int g = 2 * w + i2;
            const float* srow = &Smix[(g * 16 + l16) * 20];
            float s[16];
            #pragma unroll
            for (int c = 0; c < 4; ++c) {
                float4 v4 = *(const float4*)(srow + c * 4);
                s[4 * c] = v4.x; s[4 * c + 1] = v4.y; s[4 * c + 2] = v4.z; s[4 * c + 3] = v4.w;
            }
            float tmax = s[0];
            #pragma unroll
            for (int m = 1; m < 16; ++m) tmax = fmaxf(tmax, s[m]);
            float mnew = fmaxf(mrun, tmax);
            corr = __expf(mrun - mnew);
            float psum = 0.f;
            short pb[16];
            #pragma unroll
            for (int m = 0; m < 16; ++m) {
                float p = __expf(s[m] - mnew);
                psum += p;
                pb[m] = f2bf(p);
            }
            srun = srun * corr + psum;
            mrun = mnew;
            short* pd = &Plds[(g * 16 + l16) * 20];
            #pragma unroll
            for (int c = 0; c < 4; ++c) {
                bf16x4 pk = { pb[4 * c], pb[4 * c + 1], pb[4 * c + 2], pb[4 * c + 3] };
                *(bf16x4*)&pd[c * 4] = pk;
            }
        }
        __syncthreads();

        // --- PV: D[d][l] per g; A = Vt rows d, B = P^T cols l; rescale acc by corr
        #pragma unroll
        for (int i = 0; i < 2; ++i) {
            int g = 2 * w + i;
            float cg_ = __shfl(corr, (i << 4) | l16);
            bf16x4 bfr = *(const bf16x4*)&Plds[(g * 16 + l16) * 20 + qq * 4];
            #pragma unroll
            for (int dt = 0; dt < 4; ++dt) {
                acc[i][dt] *= cg_;
                bf16x4 afr = *(const bf16x4*)&Vts[(g * 64 + dt * 16 + l16) * 20 + qq * 4];
                acc[i][dt] = __builtin_amdgcn_mfma_f32_16x16x16bf16_1k(afr, bfr, acc[i][dt], 0, 0, 0);
            }
        }
        __syncthreads();
    }

    // --- epilogue: out bf16 [b][l][g*64+d]
    #pragma unroll
    for (int i = 0; i < 2; ++i) {
        int g = 2 * w + i;
        float inv = 1.f / __shfl(srun, (i << 4) | l16);
        #pragma unroll
        for (int dt = 0; dt < 4; ++dt) {
            f32x4 a = acc[i][dt];
            bf16x4 ov = { f2bf(a[0] * inv), f2bf(a[1] * inv), f2bf(a[2] * inv), f2bf(a[3] * inv) };
            size_t o = ((size_t)b * L_ + l0 + l16) * (size_t)D_ + g * 64 + dt * 16 + qq * 4;
            *(bf16x4*)&attn_out[o] = ov;
        }
    }
}

// ---------------------------------------------------------------------------
// Kernel 3: output projection (attn bf16 @ Wo^T + bo) -> f32, MFMA.
// ---------------------------------------------------------------------------
__global__ __launch_bounds__(256) void out_mfma(
    const short* __restrict__ attn, const float* __restrict__ Wo,
    const float* __restrict__ bo, float* __restrict__ out)
{
    __shared__ short Ws[128][40];
    __shared__ short Xs[128][40];

    const int tid = threadIdx.x;
    const int w = tid >> 6, lane = tid & 63;
    const int l16 = lane & 15, qq = lane >> 4;
    const int m0 = blockIdx.x * 128;
    const int n0 = blockIdx.y * 128;
    const int ar0 = 64 * (w & 1);
    const int br0 = 64 * (w >> 1);

    f32x4 acc[4][4] = {};

    for (int k0 = 0; k0 < D_; k0 += 32) {
        #pragma unroll
        for (int i = 0; i < 4; ++i) {
            int fidx = i * 256 + tid;
            int r = fidx >> 3, c = fidx & 7;
            float4 wv4 = *(const float4*)(Wo + (size_t)(n0 + r) * D_ + k0 + c * 4);
            bf16x4 wb = { f2bf(wv4.x), f2bf(wv4.y), f2bf(wv4.z), f2bf(wv4.w) };
            *(bf16x4*)&Ws[r][c * 4] = wb;
        }
        #pragma unroll
        for (int i = 0; i < 2; ++i) {
            int cidx = i * 256 + tid;
            int r = cidx >> 2, c = cidx & 3;
            bf16x8 xv = *(const bf16x8*)(attn + (size_t)(m0 + r) * D_ + k0 + c * 8);
            *(bf16x8*)&Xs[r][c * 8] = xv;
        }
        __syncthreads();
        bf16x8 af[4], bf[4];
        #pragma unroll
        for (int i = 0; i < 4; ++i) {
            af[i] = *(const bf16x8*)&Ws[ar0 + 16 * i + l16][qq * 8];
            bf[i] = *(const bf16x8*)&Xs[br0 + 16 * i + l16][qq * 8];
        }
        #pragma unroll
        for (int i = 0; i < 4; ++i)
            #pragma unroll
            for (int j = 0; j < 4; ++j)
                acc[i][j] = __builtin_amdgcn_mfma_f32_16x16x32_bf16(af[i], bf[j], acc[i][j], 0, 0, 0);
        __syncthreads();
    }

    #pragma unroll
    for (int i = 0; i < 4; ++i) {
        int nb = n0 + ar0 + 16 * i + qq * 4;
        float4 b4 = *(const float4*)(bo + nb);
        #pragma unroll
        for (int j = 0; j < 4; ++j) {
            int m = m0 + br0 + 16 * j + l16;
            f32x4 c = acc[i][j];
            float4 ov = make_float4(c[0] + b4.x, c[1] + b4.y, c[2] + b4.z, c[3] + b4.w);
            *(float4*)&out[(size_t)m * D_ + nb] = ov;
        }
    }
}

// ---------------------------------------------------------------------------
extern "C" void kernel_launch(void* const* d_in, const int* in_sizes, int n_in,
                              void* d_out, int out_size, void* d_ws, size_t ws_size,
                              hipStream_t stream) {
    const float* q  = (const float*)d_in[0];
    const float* k  = (const float*)d_in[1];
    const float* v  = (const float*)d_in[2];
    const float* Wq = (const float*)d_in[3];
    const float* bq = (const float*)d_in[4];
    const float* Wk = (const float*)d_in[5];
    const float* bk = (const float*)d_in[6];
    const float* Wv = (const float*)d_in[7];
    const float* bv = (const float*)d_in[8];
    const float* Wo = (const float*)d_in[9];
    const float* bo = (const float*)d_in[10];
    const float* P  = (const float*)d_in[11];
    float* out = (float*)d_out;

    // ws: qh 8MB | qlo 8MB | kh 8MB | vht 8MB | attn 8MB   (all bf16/short)
    char* ws = (char*)d_ws;
    short* qh   = (short*)(ws);
    short* qlo  = (short*)(ws + (size_t)8 * 1024 * 1024);
    short* kh   = (short*)(ws + (size_t)16 * 1024 * 1024);
    short* vht  = (short*)(ws + (size_t)24 * 1024 * 1024);
    short* attn = (short*)(ws + (size_t)32 * 1024 * 1024);

    proj_mfma<<<dim3(M_ / 128, D_ / 128, 3), 256, 0, stream>>>(
        q, k, v, Wq, bq, Wk, bk, Wv, bv, qh, qlo, kh, vht);
    attn_mfma<<<dim3(L_ / 16, B_), 512, 0, stream>>>(qh, qlo, kh, vht, P, attn);
    out_mfma<<<dim3(M_ / 128, D_ / 128), 256, 0, stream>>>(attn, Wo, bo, out);
}

// Round 6
// 436.648 us; speedup vs baseline: 8.7548x; 1.6120x over previous
//
#include <hip/hip_runtime.h>

#define D_  1024
#define H_  16
#define HD_ 64
#define L_  2048
#define B_  2
#define M_  (B_*L_)   // 4096 rows

typedef float f32x4  __attribute__((ext_vector_type(4)));
typedef short bf16x4 __attribute__((ext_vector_type(4)));
typedef short bf16x8 __attribute__((ext_vector_type(8)));

__device__ __forceinline__ float bf2f(short s) {
    return __uint_as_float(((unsigned int)(unsigned short)s) << 16);
}
__device__ __forceinline__ short f2bf(float f) {   // RNE
    unsigned u = __float_as_uint(f);
    unsigned r = (u + 0x7FFFu + ((u >> 16) & 1u)) >> 16;
    return (short)r;
}

// ---------------------------------------------------------------------------
// Kernel 1: QKV projections via bf16 MFMA. 128x128 tile, K-step 32, 256 thr.
// z=0: q -> qh(hi)+qlo  [b][h][l][64]        (A=W rows n, B=X cols m: D[n][m])
// z=1: k -> kh          [b][h][l][64]        (same)
// z=2: v -> vht         [b][h][64][L]        (A=X rows m, B=W cols n: D[m][n],
//                                             transposed write needs m on A side)
// ---------------------------------------------------------------------------
__global__ __launch_bounds__(256) void proj_mfma(
    const float* __restrict__ q, const float* __restrict__ k, const float* __restrict__ v,
    const float* __restrict__ Wq, const float* __restrict__ bq,
    const float* __restrict__ Wk, const float* __restrict__ bk,
    const float* __restrict__ Wv, const float* __restrict__ bv,
    short* __restrict__ qh, short* __restrict__ qlo,
    short* __restrict__ kh, short* __restrict__ vht)
{
    const int z = blockIdx.z;
    const float* X    = (z == 0) ? q  : (z == 1) ? k  : v;
    const float* W    = (z == 0) ? Wq : (z == 1) ? Wk : Wv;
    const float* bias = (z == 0) ? bq : (z == 1) ? bk : bv;

    __shared__ short Ws[128][40];
    __shared__ short Xs[128][40];

    const int tid  = threadIdx.x;
    const int w    = tid >> 6, lane = tid & 63;
    const int l16  = lane & 15, qq = lane >> 4;
    const int m0   = blockIdx.x * 128;
    const int n0   = blockIdx.y * 128;
    const int ar0  = 64 * (w & 1);
    const int br0  = 64 * (w >> 1);

    f32x4 acc[4][4] = {};

    for (int k0 = 0; k0 < D_; k0 += 32) {
        #pragma unroll
        for (int i = 0; i < 4; ++i) {
            int fidx = i * 256 + tid;
            int r = fidx >> 3, c = fidx & 7;
            float4 wv4 = *(const float4*)(W + (size_t)(n0 + r) * D_ + k0 + c * 4);
            float4 xv4 = *(const float4*)(X + (size_t)(m0 + r) * D_ + k0 + c * 4);
            bf16x4 wb = { f2bf(wv4.x), f2bf(wv4.y), f2bf(wv4.z), f2bf(wv4.w) };
            bf16x4 xb = { f2bf(xv4.x), f2bf(xv4.y), f2bf(xv4.z), f2bf(xv4.w) };
            *(bf16x4*)&Ws[r][c * 4] = wb;
            *(bf16x4*)&Xs[r][c * 4] = xb;
        }
        __syncthreads();
        bf16x8 af[4], bfv[4];
        #pragma unroll
        for (int i = 0; i < 4; ++i) {
            // z<2: A=W (rows n), B=X (cols m).  z==2: A=X (rows m), B=W (cols n).
            const short* Ab = (z < 2) ? &Ws[ar0 + 16 * i + l16][qq * 8]
                                      : &Xs[ar0 + 16 * i + l16][qq * 8];
            const short* Bb = (z < 2) ? &Xs[br0 + 16 * i + l16][qq * 8]
                                      : &Ws[br0 + 16 * i + l16][qq * 8];
            af[i]  = *(const bf16x8*)Ab;
            bfv[i] = *(const bf16x8*)Bb;
        }
        #pragma unroll
        for (int i = 0; i < 4; ++i)
            #pragma unroll
            for (int j = 0; j < 4; ++j)
                acc[i][j] = __builtin_amdgcn_mfma_f32_16x16x32_bf16(af[i], bfv[j], acc[i][j], 0, 0, 0);
        __syncthreads();
    }

    if (z < 2) {
        // D[n][l]: rows n = n0+ar0+16i+4qq+r ; cols m = m0+br0+16j+l16
        #pragma unroll
        for (int i = 0; i < 4; ++i) {
            int nb = n0 + ar0 + 16 * i + qq * 4;
            float4 b4 = *(const float4*)(bias + nb);
            int h = nb >> 6, hd = nb & 63;
            #pragma unroll
            for (int j = 0; j < 4; ++j) {
                int m = m0 + br0 + 16 * j + l16;
                int bb = m >> 11, l = m & (L_ - 1);
                size_t o = ((((size_t)bb * H_ + h) * L_) + l) * HD_ + hd;
                f32x4 c = acc[i][j];
                float v0 = c[0] + b4.x, v1 = c[1] + b4.y, v2 = c[2] + b4.z, v3 = c[3] + b4.w;
                bf16x4 hi = { f2bf(v0), f2bf(v1), f2bf(v2), f2bf(v3) };
                if (z == 0) {
                    *(bf16x4*)&qh[o] = hi;
                    bf16x4 lo = { f2bf(v0 - bf2f(hi[0])), f2bf(v1 - bf2f(hi[1])),
                                  f2bf(v2 - bf2f(hi[2])), f2bf(v3 - bf2f(hi[3])) };
                    *(bf16x4*)&qlo[o] = lo;
                } else {
                    *(bf16x4*)&kh[o] = hi;
                }
            }
        }
    } else {
        // D[m][n]: rows m = m0+ar0+16i+4qq+r ; cols n = n0+br0+16j+l16
        #pragma unroll
        for (int i = 0; i < 4; ++i) {
            int mb = m0 + ar0 + 16 * i + qq * 4;
            int bb = mb >> 11, lb = mb & (L_ - 1);
            #pragma unroll
            for (int j = 0; j < 4; ++j) {
                int n = n0 + br0 + 16 * j + l16;
                int h = n >> 6, hd = n & 63;
                float bn = bias[n];
                size_t o = (((size_t)bb * H_ + h) * HD_ + hd) * (size_t)L_ + lb;
                f32x4 c = acc[i][j];
                bf16x4 ov = { f2bf(c[0] + bn), f2bf(c[1] + bn), f2bf(c[2] + bn), f2bf(c[3] + bn) };
                *(bf16x4*)&vht[o] = ov;
            }
        }
    }
}

// ---------------------------------------------------------------------------
// Kernel 2: fused talking-heads attention. 512 thr (8 waves), l-tile 16,
// m-tile 16, all heads per block. Wave w: heads/g {2w, 2w+1}.
// K: global->reg double-buffer (no LDS). V^T: global -> reg -> per-wave LDS
// slab -> ds_read A-fragments. Mix + softmax fully in registers (shfl).
// ---------------------------------------------------------------------------
__global__ __launch_bounds__(512, 2) void attn_mfma(
    const short* __restrict__ qh, const short* __restrict__ qlo,
    const short* __restrict__ kh, const short* __restrict__ vht,
    const float* __restrict__ P, short* __restrict__ attn_out)
{
    __shared__ __align__(16) float Sraw[16 * 16 * 20];    // [h][l][20] f32, 20.5 KB
    __shared__ __align__(16) short Vslab[8][2 * 64 * 24]; // per-wave [g2][d64][16m+8pad], 48 KB
    __shared__ float PmS[256];

    const int tid  = threadIdx.x;
    const int n    = blockIdx.x;
    const int b    = (n >> 2) & 1;                        // XCD swizzle: XCD0-3 -> b0, 4-7 -> b1
    const int l0   = ((n >> 3) * 4 + (n & 3)) * 16;
    const int w    = tid >> 6, lane = tid & 63;
    const int l16  = lane & 15, qq = lane >> 4;
    const size_t hb = (size_t)b * H_;

    // ---- early global issues: Q frags (persistent), K0, V0
    bf16x8 qf[2][2][2];
    #pragma unroll
    for (int hh = 0; hh < 2; ++hh)
        #pragma unroll
        for (int kc = 0; kc < 2; ++kc) {
            size_t off = ((hb + 2 * w + hh) * L_ + l0 + l16) * HD_ + kc * 32 + qq * 8;
            qf[hh][kc][0] = *(const bf16x8*)(qh  + off);
            qf[hh][kc][1] = *(const bf16x8*)(qlo + off);
        }
    bf16x8 kcur[2][2], knxt[2][2], vcur[4], vnxt[4];
    #pragma unroll
    for (int hh = 0; hh < 2; ++hh)
        #pragma unroll
        for (int kc = 0; kc < 2; ++kc)
            kcur[hh][kc] = *(const bf16x8*)(kh + ((hb + 2 * w + hh) * L_ + l16) * HD_ + kc * 32 + qq * 8);
    // V^T staging mapping: i in 0..3 -> row = i*32 + (lane>>1) of 128 rows
    // (gi = row>>6 head-half, d = row&63), c = lane&1 (16B chunk of the 32B row)
    int vgi_[4], vd_[4];
    const int vc = lane & 1;
    #pragma unroll
    for (int i = 0; i < 4; ++i) {
        int vrow = i * 32 + (lane >> 1);
        vgi_[i] = vrow >> 6;
        vd_[i]  = vrow & 63;
    }
    #pragma unroll
    for (int i = 0; i < 4; ++i)
        vcur[i] = *(const bf16x8*)(vht + ((hb + 2 * w + vgi_[i]) * HD_ + vd_[i]) * (size_t)L_ + vc * 8);

    if (tid < 256) PmS[tid] = P[tid] * 0.125f;            // fold 1/sqrt(64)
    __syncthreads();

    float pw0[16], pw1[16];
    #pragma unroll
    for (int h = 0; h < 16; ++h) {
        pw0[h] = PmS[h * 16 + 2 * w];
        pw1[h] = PmS[h * 16 + 2 * w + 1];
    }

    f32x4 acc[2][4];
    #pragma unroll
    for (int dt = 0; dt < 4; ++dt) { acc[0][dt] = (f32x4){0.f,0.f,0.f,0.f}; acc[1][dt] = (f32x4){0.f,0.f,0.f,0.f}; }
    float mrun0 = -1e30f, mrun1 = -1e30f, srun0 = 0.f, srun1 = 0.f;

    // LDS slab offsets (shorts): write rows, read A-fragments
    int vwoff[4];
    #pragma unroll
    for (int i = 0; i < 4; ++i)
        vwoff[i] = vgi_[i] * (64 * 24) + vd_[i] * 24 + vc * 8;

    for (int it = 0; it < 128; ++it) {
        const int mn = ((it + 1) & 127) * 16;
        // 1. stage current V^T into per-wave slab
        #pragma unroll
        for (int i = 0; i < 4; ++i)
            *(bf16x8*)&Vslab[w][vwoff[i]] = vcur[i];
        // 2. QK^T (regs only) -> Sraw.  D[m][l]: col=l16=l, row=qq*4+j=m
        #pragma unroll
        for (int hh = 0; hh < 2; ++hh) {
            f32x4 s = (f32x4){0.f,0.f,0.f,0.f};
            s = __builtin_amdgcn_mfma_f32_16x16x32_bf16(kcur[hh][0], qf[hh][0][0], s, 0, 0, 0);
            s = __builtin_amdgcn_mfma_f32_16x16x32_bf16(kcur[hh][0], qf[hh][0][1], s, 0, 0, 0);
            s = __builtin_amdgcn_mfma_f32_16x16x32_bf16(kcur[hh][1], qf[hh][1][0], s, 0, 0, 0);
            s = __builtin_amdgcn_mfma_f32_16x16x32_bf16(kcur[hh][1], qf[hh][1][1], s, 0, 0, 0);
            *(f32x4*)&Sraw[((2 * w + hh) * 16 + l16) * 20 + qq * 4] = s;
        }
        __syncthreads();   // B1: Sraw visible to all waves
        // 3. prefetch next K/V tiles (global -> regs); B2's drain gives them
        //    the whole mix+softmax+PV window to land
        #pragma unroll
        for (int hh = 0; hh < 2; ++hh)
            #pragma unroll
            for (int kc = 0; kc < 2; ++kc)
                knxt[hh][kc] = *(const bf16x8*)(kh + ((hb + 2 * w + hh) * L_ + mn + l16) * HD_ + kc * 32 + qq * 8);
        #pragma unroll
        for (int i = 0; i < 4; ++i)
            vnxt[i] = *(const bf16x8*)(vht + ((hb + 2 * w + vgi_[i]) * HD_ + vd_[i]) * (size_t)L_ + mn + vc * 8);
        // 4. talking-heads mix: lane (l=l16, m-quad=qq), 2 g per lane in regs
        float sx0[4] = {0.f,0.f,0.f,0.f}, sx1[4] = {0.f,0.f,0.f,0.f};
        #pragma unroll
        for (int h = 0; h < 16; ++h) {
            f32x4 c = *(const f32x4*)&Sraw[(h * 16 + l16) * 20 + qq * 4];
            #pragma unroll
            for (int j = 0; j < 4; ++j) { sx0[j] += pw0[h] * c[j]; sx1[j] += pw1[h] * c[j]; }
        }
        // 5. online softmax (row reduce over m via qq-lane shfl_xor 16/32)
        float t0 = fmaxf(fmaxf(sx0[0], sx0[1]), fmaxf(sx0[2], sx0[3]));
        float t1 = fmaxf(fmaxf(sx1[0], sx1[1]), fmaxf(sx1[2], sx1[3]));
        t0 = fmaxf(t0, __shfl_xor(t0, 16)); t0 = fmaxf(t0, __shfl_xor(t0, 32));
        t1 = fmaxf(t1, __shfl_xor(t1, 16)); t1 = fmaxf(t1, __shfl_xor(t1, 32));
        float mnew0 = fmaxf(mrun0, t0), mnew1 = fmaxf(mrun1, t1);
        float corr0 = __expf(mrun0 - mnew0), corr1 = __expf(mrun1 - mnew1);
        float e00 = __expf(sx0[0] - mnew0), e01 = __expf(sx0[1] - mnew0);
        float e02 = __expf(sx0[2] - mnew0), e03 = __expf(sx0[3] - mnew0);
        float e10 = __expf(sx1[0] - mnew1), e11 = __expf(sx1[1] - mnew1);
        float e12 = __expf(sx1[2] - mnew1), e13 = __expf(sx1[3] - mnew1);
        float ps0 = e00 + e01 + e02 + e03, ps1 = e10 + e11 + e12 + e13;
        ps0 += __shfl_xor(ps0, 16); ps0 += __shfl_xor(ps0, 32);
        ps1 += __shfl_xor(ps1, 16); ps1 += __shfl_xor(ps1, 32);
        srun0 = srun0 * corr0 + ps0; srun1 = srun1 * corr1 + ps1;
        mrun0 = mnew0; mrun1 = mnew1;
        // P fragment is already lane-correct for PV B-operand: (l=l16, m=qq*4+j)
        bf16x4 pf0 = { f2bf(e00), f2bf(e01), f2bf(e02), f2bf(e03) };
        bf16x4 pf1 = { f2bf(e10), f2bf(e11), f2bf(e12), f2bf(e13) };
        // 6. PV: A = V^T (rows d, k=m) from slab, B = pf.  D[d][l], col=l16.
        acc[0][0] *= corr0; acc[0][1] *= corr0; acc[0][2] *= corr0; acc[0][3] *= corr0;
        acc[1][0] *= corr1; acc[1][1] *= corr1; acc[1][2] *= corr1; acc[1][3] *= corr1;
        #pragma unroll
        for (int i = 0; i < 2; ++i) {
            bf16x4 pf = i ? pf1 : pf0;
            #pragma unroll
            for (int dt = 0; dt < 4; ++dt) {
                bf16x4 afr = *(const bf16x4*)&Vslab[w][i * (64 * 24) + (dt * 16 + l16) * 24 + qq * 4];
                acc[i][dt] = __builtin_amdgcn_mfma_f32_16x16x16bf16_1k(afr, pf, acc[i][dt], 0, 0, 0);
            }
        }
        __syncthreads();   // B2: Sraw reads done; prefetch drained -> safe to rotate
        #pragma unroll
        for (int hh = 0; hh < 2; ++hh)
            #pragma unroll
            for (int kc = 0; kc < 2; ++kc) kcur[hh][kc] = knxt[hh][kc];
        #pragma unroll
        for (int i = 0; i < 4; ++i) vcur[i] = vnxt[i];
    }

    // epilogue: D[d][l] -> out[b][l][g*64 + d], d = dt*16 + qq*4 + j, l = l16
    float inv0 = 1.f / srun0, inv1 = 1.f / srun1;
    #pragma unroll
    for (int i = 0; i < 2; ++i) {
        float inv = i ? inv1 : inv0;
        #pragma unroll
        for (int dt = 0; dt < 4; ++dt) {
            f32x4 a = acc[i][dt];
            bf16x4 ov = { f2bf(a[0] * inv), f2bf(a[1] * inv), f2bf(a[2] * inv), f2bf(a[3] * inv) };
            *(bf16x4*)(attn_out + ((size_t)(b * L_ + l0 + l16)) * D_ + (2 * w + i) * 64 + dt * 16 + qq * 4) = ov;
        }
    }
}

// ---------------------------------------------------------------------------
// Kernel 3: output projection (attn bf16 @ Wo^T + bo) -> f32, MFMA.
// ---------------------------------------------------------------------------
__global__ __launch_bounds__(256) void out_mfma(
    const short* __restrict__ attn, const float* __restrict__ Wo,
    const float* __restrict__ bo, float* __restrict__ out)
{
    __shared__ short Ws[128][40];
    __shared__ short Xs[128][40];

    const int tid = threadIdx.x;
    const int w = tid >> 6, lane = tid & 63;
    const int l16 = lane & 15, qq = lane >> 4;
    const int m0 = blockIdx.x * 128;
    const int n0 = blockIdx.y * 128;
    const int ar0 = 64 * (w & 1);
    const int br0 = 64 * (w >> 1);

    f32x4 acc[4][4] = {};

    for (int k0 = 0; k0 < D_; k0 += 32) {
        #pragma unroll
        for (int i = 0; i < 4; ++i) {
            int fidx = i * 256 + tid;
            int r = fidx >> 3, c = fidx & 7;
            float4 wv4 = *(const float4*)(Wo + (size_t)(n0 + r) * D_ + k0 + c * 4);
            bf16x4 wb = { f2bf(wv4.x), f2bf(wv4.y), f2bf(wv4.z), f2bf(wv4.w) };
            *(bf16x4*)&Ws[r][c * 4] = wb;
        }
        #pragma unroll
        for (int i = 0; i < 2; ++i) {
            int cidx = i * 256 + tid;
            int r = cidx >> 2, c = cidx & 3;
            bf16x8 xv = *(const bf16x8*)(attn + (size_t)(m0 + r) * D_ + k0 + c * 8);
            *(bf16x8*)&Xs[r][c * 8] = xv;
        }
        __syncthreads();
        bf16x8 af[4], bfv[4];
        #pragma unroll
        for (int i = 0; i < 4; ++i) {
            af[i]  = *(const bf16x8*)&Ws[ar0 + 16 * i + l16][qq * 8];
            bfv[i] = *(const bf16x8*)&Xs[br0 + 16 * i + l16][qq * 8];
        }
        #pragma unroll
        for (int i = 0; i < 4; ++i)
            #pragma unroll
            for (int j = 0; j < 4; ++j)
                acc[i][j] = __builtin_amdgcn_mfma_f32_16x16x32_bf16(af[i], bfv[j], acc[i][j], 0, 0, 0);
        __syncthreads();
    }

    #pragma unroll
    for (int i = 0; i < 4; ++i) {
        int nb = n0 + ar0 + 16 * i + qq * 4;
        float4 b4 = *(const float4*)(bo + nb);
        #pragma unroll
        for (int j = 0; j < 4; ++j) {
            int m = m0 + br0 + 16 * j + l16;
            f32x4 c = acc[i][j];
            float4 ov = make_float4(c[0] + b4.x, c[1] + b4.y, c[2] + b4.z, c[3] + b4.w);
            *(float4*)&out[(size_t)m * D_ + nb] = ov;
        }
    }
}

// ---------------------------------------------------------------------------
extern "C" void kernel_launch(void* const* d_in, const int* in_sizes, int n_in,
                              void* d_out, int out_size, void* d_ws, size_t ws_size,
                              hipStream_t stream) {
    const float* q  = (const float*)d_in[0];
    const float* k  = (const float*)d_in[1];
    const float* v  = (const float*)d_in[2];
    const float* Wq = (const float*)d_in[3];
    const float* bq = (const float*)d_in[4];
    const float* Wk = (const float*)d_in[5];
    const float* bk = (const float*)d_in[6];
    const float* Wv = (const float*)d_in[7];
    const float* bv = (const float*)d_in[8];
    const float* Wo = (const float*)d_in[9];
    const float* bo = (const float*)d_in[10];
    const float* P  = (const float*)d_in[11];
    float* out = (float*)d_out;

    // ws: qh 8MB | qlo 8MB | kh 8MB | vht 8MB | attn 8MB (all bf16/short)
    char* ws = (char*)d_ws;
    short* qh   = (short*)(ws);
    short* qlo  = (short*)(ws + (size_t)8 * 1024 * 1024);
    short* kh   = (short*)(ws + (size_t)16 * 1024 * 1024);
    short* vht  = (short*)(ws + (size_t)24 * 1024 * 1024);
    short* attn = (short*)(ws + (size_t)32 * 1024 * 1024);

    proj_mfma<<<dim3(M_ / 128, D_ / 128, 3), 256, 0, stream>>>(
        q, k, v, Wq, bq, Wk, bk, Wv, bv, qh, qlo, kh, vht);
    attn_mfma<<<dim3(256), 512, 0, stream>>>(qh, qlo, kh, vht, P, attn);
    out_mfma<<<dim3(M_ / 128, D_ / 128), 256, 0, stream>>>(attn, Wo, bo, out);
}

// Round 7
// 434.913 us; speedup vs baseline: 8.7897x; 1.0040x over previous
//
#include <hip/hip_runtime.h>

#define D_  1024
#define H_  16
#define HD_ 64
#define L_  2048
#define B_  2
#define M_  (B_*L_)   // 4096 rows

typedef float f32x4  __attribute__((ext_vector_type(4)));
typedef short bf16x4 __attribute__((ext_vector_type(4)));
typedef short bf16x8 __attribute__((ext_vector_type(8)));

#define SRAW_PITCH 18   // dwords per l-row (72B): odd/2 stride -> conflict-free b64
#define VS_PITCH   36   // shorts per d-row (72B): same property

__device__ __forceinline__ float bf2f(short s) {
    return __uint_as_float(((unsigned int)(unsigned short)s) << 16);
}
__device__ __forceinline__ short f2bf(float f) {   // RNE
    unsigned u = __float_as_uint(f);
    unsigned r = (u + 0x7FFFu + ((u >> 16) & 1u)) >> 16;
    return (short)r;
}

// ---------------------------------------------------------------------------
// Kernel 1: QKV projections via bf16 MFMA. 128x128 tile, K-step 32, 256 thr.
// z=0: q -> qh(hi)+qlo  [b][h][l][64]        (A=W rows n, B=X cols m: D[n][m])
// z=1: k -> kh          [b][h][l][64]        (same)
// z=2: v -> vht         [b][h][64][L]        (A=X rows m, B=W cols n: D[m][n])
// ---------------------------------------------------------------------------
__global__ __launch_bounds__(256) void proj_mfma(
    const float* __restrict__ q, const float* __restrict__ k, const float* __restrict__ v,
    const float* __restrict__ Wq, const float* __restrict__ bq,
    const float* __restrict__ Wk, const float* __restrict__ bk,
    const float* __restrict__ Wv, const float* __restrict__ bv,
    short* __restrict__ qh, short* __restrict__ qlo,
    short* __restrict__ kh, short* __restrict__ vht)
{
    const int z = blockIdx.z;
    const float* X    = (z == 0) ? q  : (z == 1) ? k  : v;
    const float* W    = (z == 0) ? Wq : (z == 1) ? Wk : Wv;
    const float* bias = (z == 0) ? bq : (z == 1) ? bk : bv;

    __shared__ short Ws[128][40];
    __shared__ short Xs[128][40];

    const int tid  = threadIdx.x;
    const int w    = tid >> 6, lane = tid & 63;
    const int l16  = lane & 15, qq = lane >> 4;
    const int m0   = blockIdx.x * 128;
    const int n0   = blockIdx.y * 128;
    const int ar0  = 64 * (w & 1);
    const int br0  = 64 * (w >> 1);

    f32x4 acc[4][4] = {};

    for (int k0 = 0; k0 < D_; k0 += 32) {
        #pragma unroll
        for (int i = 0; i < 4; ++i) {
            int fidx = i * 256 + tid;
            int r = fidx >> 3, c = fidx & 7;
            float4 wv4 = *(const float4*)(W + (size_t)(n0 + r) * D_ + k0 + c * 4);
            float4 xv4 = *(const float4*)(X + (size_t)(m0 + r) * D_ + k0 + c * 4);
            bf16x4 wb = { f2bf(wv4.x), f2bf(wv4.y), f2bf(wv4.z), f2bf(wv4.w) };
            bf16x4 xb = { f2bf(xv4.x), f2bf(xv4.y), f2bf(xv4.z), f2bf(xv4.w) };
            *(bf16x4*)&Ws[r][c * 4] = wb;
            *(bf16x4*)&Xs[r][c * 4] = xb;
        }
        __syncthreads();
        bf16x8 af[4], bfv[4];
        #pragma unroll
        for (int i = 0; i < 4; ++i) {
            // z<2: A=W (rows n), B=X (cols m).  z==2: A=X (rows m), B=W (cols n).
            const short* Ab = (z < 2) ? &Ws[ar0 + 16 * i + l16][qq * 8]
                                      : &Xs[ar0 + 16 * i + l16][qq * 8];
            const short* Bb = (z < 2) ? &Xs[br0 + 16 * i + l16][qq * 8]
                                      : &Ws[br0 + 16 * i + l16][qq * 8];
            af[i]  = *(const bf16x8*)Ab;
            bfv[i] = *(const bf16x8*)Bb;
        }
        #pragma unroll
        for (int i = 0; i < 4; ++i)
            #pragma unroll
            for (int j = 0; j < 4; ++j)
                acc[i][j] = __builtin_amdgcn_mfma_f32_16x16x32_bf16(af[i], bfv[j], acc[i][j], 0, 0, 0);
        __syncthreads();
    }

    if (z < 2) {
        #pragma unroll
        for (int i = 0; i < 4; ++i) {
            int nb = n0 + ar0 + 16 * i + qq * 4;
            float4 b4 = *(const float4*)(bias + nb);
            int h = nb >> 6, hd = nb & 63;
            #pragma unroll
            for (int j = 0; j < 4; ++j) {
                int m = m0 + br0 + 16 * j + l16;
                int bb = m >> 11, l = m & (L_ - 1);
                size_t o = ((((size_t)bb * H_ + h) * L_) + l) * HD_ + hd;
                f32x4 c = acc[i][j];
                float v0 = c[0] + b4.x, v1 = c[1] + b4.y, v2 = c[2] + b4.z, v3 = c[3] + b4.w;
                bf16x4 hi = { f2bf(v0), f2bf(v1), f2bf(v2), f2bf(v3) };
                if (z == 0) {
                    *(bf16x4*)&qh[o] = hi;
                    bf16x4 lo = { f2bf(v0 - bf2f(hi[0])), f2bf(v1 - bf2f(hi[1])),
                                  f2bf(v2 - bf2f(hi[2])), f2bf(v3 - bf2f(hi[3])) };
                    *(bf16x4*)&qlo[o] = lo;
                } else {
                    *(bf16x4*)&kh[o] = hi;
                }
            }
        }
    } else {
        // D[m][n]: rows m = m0+ar0+16i+4qq+r ; cols n = n0+br0+16j+l16
        #pragma unroll
        for (int i = 0; i < 4; ++i) {
            int mb = m0 + ar0 + 16 * i + qq * 4;
            int bb = mb >> 11, lb = mb & (L_ - 1);
            #pragma unroll
            for (int j = 0; j < 4; ++j) {
                int n = n0 + br0 + 16 * j + l16;
                int h = n >> 6, hd = n & 63;
                float bn = bias[n];
                size_t o = (((size_t)bb * H_ + h) * HD_ + hd) * (size_t)L_ + lb;
                f32x4 c = acc[i][j];
                bf16x4 ov = { f2bf(c[0] + bn), f2bf(c[1] + bn), f2bf(c[2] + bn), f2bf(c[3] + bn) };
                *(bf16x4*)&vht[o] = ov;
            }
        }
    }
}

// ---------------------------------------------------------------------------
// Kernel 2: fused talking-heads attention. 512 thr (8 waves), l-tile 16,
// m-tile 16, all heads per block. Wave w: heads/g {2w, 2w+1}.
// R7: conflict-free LDS pitches (72B rows, b64 access), Sraw double-buffer,
// ONE __syncthreads per m-tile, prefetch issued early in the body.
// ---------------------------------------------------------------------------
__global__ __launch_bounds__(512, 2) void attn_mfma(
    const short* __restrict__ qh, const short* __restrict__ qlo,
    const short* __restrict__ kh, const short* __restrict__ vht,
    const float* __restrict__ P, short* __restrict__ attn_out)
{
    __shared__ __align__(16) float Sraw0[16 * 16 * SRAW_PITCH];   // 18.4 KB
    __shared__ __align__(16) float Sraw1[16 * 16 * SRAW_PITCH];   // 18.4 KB
    __shared__ __align__(16) short Vslab[8][2 * 64 * VS_PITCH];   // 73.7 KB
    __shared__ float PmS[256];

    const int tid  = threadIdx.x;
    const int n    = blockIdx.x;
    const int b    = (n >> 2) & 1;                        // XCD swizzle
    const int l0   = ((n >> 3) * 4 + (n & 3)) * 16;
    const int w    = tid >> 6, lane = tid & 63;
    const int l16  = lane & 15, qq = lane >> 4;
    const size_t hb = (size_t)b * H_;

    // ---- Q frags (persistent)
    bf16x8 qf[2][2][2];
    #pragma unroll
    for (int hh = 0; hh < 2; ++hh)
        #pragma unroll
        for (int kc = 0; kc < 2; ++kc) {
            size_t off = ((hb + 2 * w + hh) * L_ + l0 + l16) * HD_ + kc * 32 + qq * 8;
            qf[hh][kc][0] = *(const bf16x8*)(qh  + off);
            qf[hh][kc][1] = *(const bf16x8*)(qlo + off);
        }

    // V^T staging mapping (i: row = i*32 + (lane>>1); gi = row>>6, d = row&63; vc = lane&1)
    int vgi_[4], vd_[4];
    const int vc = lane & 1;
    #pragma unroll
    for (int i = 0; i < 4; ++i) {
        int vrow = i * 32 + (lane >> 1);
        vgi_[i] = vrow >> 6;
        vd_[i]  = vrow & 63;
    }
    int vwoff[4];
    #pragma unroll
    for (int i = 0; i < 4; ++i)
        vwoff[i] = vgi_[i] * (64 * VS_PITCH) + vd_[i] * VS_PITCH + vc * 8;

    // ---- double-buffered K/V registers: A = even tiles, B = odd tiles
    bf16x8 kA[2][2], kB[2][2], vA[4], vB[4];
    #pragma unroll
    for (int hh = 0; hh < 2; ++hh)
        #pragma unroll
        for (int kc = 0; kc < 2; ++kc) {
            kA[hh][kc] = *(const bf16x8*)(kh + ((hb + 2 * w + hh) * L_ + 0  + l16) * HD_ + kc * 32 + qq * 8);
            kB[hh][kc] = *(const bf16x8*)(kh + ((hb + 2 * w + hh) * L_ + 16 + l16) * HD_ + kc * 32 + qq * 8);
        }
    #pragma unroll
    for (int i = 0; i < 4; ++i) {
        vA[i] = *(const bf16x8*)(vht + ((hb + 2 * w + vgi_[i]) * HD_ + vd_[i]) * (size_t)L_ + 0  + vc * 8);
        vB[i] = *(const bf16x8*)(vht + ((hb + 2 * w + vgi_[i]) * HD_ + vd_[i]) * (size_t)L_ + 16 + vc * 8);
    }

    if (tid < 256) PmS[tid] = P[tid] * 0.125f;            // fold 1/sqrt(64)

    f32x4 acc[2][4];
    #pragma unroll
    for (int dt = 0; dt < 4; ++dt) { acc[0][dt] = (f32x4){0.f,0.f,0.f,0.f}; acc[1][dt] = (f32x4){0.f,0.f,0.f,0.f}; }
    float mrun0 = -1e30f, mrun1 = -1e30f, srun0 = 0.f, srun1 = 0.f;

    // QK^T: D[m][l], col=l16, rows m=qq*4+j.  Writes as 2x b64 (rows 72B).
    auto qkt = [&](bf16x8 (&kr)[2][2], float* sb) {
        #pragma unroll
        for (int hh = 0; hh < 2; ++hh) {
            f32x4 s = (f32x4){0.f,0.f,0.f,0.f};
            s = __builtin_amdgcn_mfma_f32_16x16x32_bf16(kr[hh][0], qf[hh][0][0], s, 0, 0, 0);
            s = __builtin_amdgcn_mfma_f32_16x16x32_bf16(kr[hh][0], qf[hh][0][1], s, 0, 0, 0);
            s = __builtin_amdgcn_mfma_f32_16x16x32_bf16(kr[hh][1], qf[hh][1][0], s, 0, 0, 0);
            s = __builtin_amdgcn_mfma_f32_16x16x32_bf16(kr[hh][1], qf[hh][1][1], s, 0, 0, 0);
            float* sp = sb + ((2 * w + hh) * 16 + l16) * SRAW_PITCH + qq * 4;
            *(float2*)sp       = make_float2(s[0], s[1]);
            *(float2*)(sp + 2) = make_float2(s[2], s[3]);
        }
    };

    // prologue: QK^T(tile 0) -> Sraw0, publish with one barrier
    qkt(kA, Sraw0);
    __syncthreads();

    float pw0[16], pw1[16];
    #pragma unroll
    for (int h = 0; h < 16; ++h) {
        pw0[h] = PmS[h * 16 + 2 * w];
        pw1[h] = PmS[h * 16 + 2 * w + 1];
    }

    // body: stage V(t); prefetch(t+2); mix/softmax/PV(t); QK^T(t+1)->other buf; barrier
    auto body = [&](float* sb, float* sbo, bf16x8 (&vstage)[4], bf16x8 (&kqk)[2][2],
                    bf16x8 (&kld)[2][2], bf16x8 (&vld)[4], int tnext) {
        // 1. stage V(t) into per-wave slab (2x b64 per 16B chunk)
        #pragma unroll
        for (int i = 0; i < 4; ++i) {
            bf16x4 wlo = { vstage[i][0], vstage[i][1], vstage[i][2], vstage[i][3] };
            bf16x4 whi = { vstage[i][4], vstage[i][5], vstage[i][6], vstage[i][7] };
            *(bf16x4*)&Vslab[w][vwoff[i]]     = wlo;
            *(bf16x4*)&Vslab[w][vwoff[i] + 4] = whi;
        }
        // 2. prefetch tile tnext (global -> regs; consumed 1-2 bodies later)
        {
            const int mn = tnext * 16;
            #pragma unroll
            for (int hh = 0; hh < 2; ++hh)
                #pragma unroll
                for (int kc = 0; kc < 2; ++kc)
                    kld[hh][kc] = *(const bf16x8*)(kh + ((hb + 2 * w + hh) * L_ + mn + l16) * HD_ + kc * 32 + qq * 8);
            #pragma unroll
            for (int i = 0; i < 4; ++i)
                vld[i] = *(const bf16x8*)(vht + ((hb + 2 * w + vgi_[i]) * HD_ + vd_[i]) * (size_t)L_ + mn + vc * 8);
        }
        // 3. talking-heads mix from sb (2x b64 per h, conflict-free pitch)
        float sx0[4] = {0.f,0.f,0.f,0.f}, sx1[4] = {0.f,0.f,0.f,0.f};
        #pragma unroll
        for (int h = 0; h < 16; ++h) {
            const float* sp = sb + (h * 16 + l16) * SRAW_PITCH + qq * 4;
            float2 ca = *(const float2*)sp;
            float2 cb = *(const float2*)(sp + 2);
            sx0[0] += pw0[h] * ca.x; sx0[1] += pw0[h] * ca.y;
            sx0[2] += pw0[h] * cb.x; sx0[3] += pw0[h] * cb.y;
            sx1[0] += pw1[h] * ca.x; sx1[1] += pw1[h] * ca.y;
            sx1[2] += pw1[h] * cb.x; sx1[3] += pw1[h] * cb.y;
        }
        // 4. online softmax (reduce over m via qq-lane shfl_xor 16/32)
        float t0 = fmaxf(fmaxf(sx0[0], sx0[1]), fmaxf(sx0[2], sx0[3]));
        float t1 = fmaxf(fmaxf(sx1[0], sx1[1]), fmaxf(sx1[2], sx1[3]));
        t0 = fmaxf(t0, __shfl_xor(t0, 16)); t0 = fmaxf(t0, __shfl_xor(t0, 32));
        t1 = fmaxf(t1, __shfl_xor(t1, 16)); t1 = fmaxf(t1, __shfl_xor(t1, 32));
        float mnew0 = fmaxf(mrun0, t0), mnew1 = fmaxf(mrun1, t1);
        float corr0 = __expf(mrun0 - mnew0), corr1 = __expf(mrun1 - mnew1);
        float e00 = __expf(sx0[0] - mnew0), e01 = __expf(sx0[1] - mnew0);
        float e02 = __expf(sx0[2] - mnew0), e03 = __expf(sx0[3] - mnew0);
        float e10 = __expf(sx1[0] - mnew1), e11 = __expf(sx1[1] - mnew1);
        float e12 = __expf(sx1[2] - mnew1), e13 = __expf(sx1[3] - mnew1);
        float ps0 = e00 + e01 + e02 + e03, ps1 = e10 + e11 + e12 + e13;
        ps0 += __shfl_xor(ps0, 16); ps0 += __shfl_xor(ps0, 32);
        ps1 += __shfl_xor(ps1, 16); ps1 += __shfl_xor(ps1, 32);
        srun0 = srun0 * corr0 + ps0; srun1 = srun1 * corr1 + ps1;
        mrun0 = mnew0; mrun1 = mnew1;
        bf16x4 pf0 = { f2bf(e00), f2bf(e01), f2bf(e02), f2bf(e03) };
        bf16x4 pf1 = { f2bf(e10), f2bf(e11), f2bf(e12), f2bf(e13) };
        // 5. PV: A = V^T rows d from slab (b64), B = pf.  D[d][l], col=l16.
        acc[0][0] *= corr0; acc[0][1] *= corr0; acc[0][2] *= corr0; acc[0][3] *= corr0;
        acc[1][0] *= corr1; acc[1][1] *= corr1; acc[1][2] *= corr1; acc[1][3] *= corr1;
        #pragma unroll
        for (int i = 0; i < 2; ++i) {
            bf16x4 pf = i ? pf1 : pf0;
            #pragma unroll
            for (int dt = 0; dt < 4; ++dt) {
                bf16x4 afr = *(const bf16x4*)&Vslab[w][i * (64 * VS_PITCH) + (dt * 16 + l16) * VS_PITCH + qq * 4];
                acc[i][dt] = __builtin_amdgcn_mfma_f32_16x16x16bf16_1k(afr, pf, acc[i][dt], 0, 0, 0);
            }
        }
        // 6. QK^T(t+1) -> other Sraw buffer, then the ONLY barrier of this body
        qkt(kqk, sbo);
        __syncthreads();
    };

    for (int itp = 0; itp < 64; ++itp) {
        const int t0 = 2 * itp;
        body(Sraw0, Sraw1, vA, kB, kA, vA, (t0 + 2) & 127);   // even tile t0
        body(Sraw1, Sraw0, vB, kA, kB, vB, (t0 + 3) & 127);   // odd tile t0+1
    }

    // epilogue: D[d][l] -> out[b][l][g*64 + d]
    float inv0 = 1.f / srun0, inv1 = 1.f / srun1;
    #pragma unroll
    for (int i = 0; i < 2; ++i) {
        float inv = i ? inv1 : inv0;
        #pragma unroll
        for (int dt = 0; dt < 4; ++dt) {
            f32x4 a = acc[i][dt];
            bf16x4 ov = { f2bf(a[0] * inv), f2bf(a[1] * inv), f2bf(a[2] * inv), f2bf(a[3] * inv) };
            *(bf16x4*)(attn_out + ((size_t)(b * L_ + l0 + l16)) * D_ + (2 * w + i) * 64 + dt * 16 + qq * 4) = ov;
        }
    }
}

// ---------------------------------------------------------------------------
// Kernel 3: output projection (attn bf16 @ Wo^T + bo) -> f32, MFMA.
// ---------------------------------------------------------------------------
__global__ __launch_bounds__(256) void out_mfma(
    const short* __restrict__ attn, const float* __restrict__ Wo,
    const float* __restrict__ bo, float* __restrict__ out)
{
    __shared__ short Ws[128][40];
    __shared__ short Xs[128][40];

    const int tid = threadIdx.x;
    const int w = tid >> 6, lane = tid & 63;
    const int l16 = lane & 15, qq = lane >> 4;
    const int m0 = blockIdx.x * 128;
    const int n0 = blockIdx.y * 128;
    const int ar0 = 64 * (w & 1);
    const int br0 = 64 * (w >> 1);

    f32x4 acc[4][4] = {};

    for (int k0 = 0; k0 < D_; k0 += 32) {
        #pragma unroll
        for (int i = 0; i < 4; ++i) {
            int fidx = i * 256 + tid;
            int r = fidx >> 3, c = fidx & 7;
            float4 wv4 = *(const float4*)(Wo + (size_t)(n0 + r) * D_ + k0 + c * 4);
            bf16x4 wb = { f2bf(wv4.x), f2bf(wv4.y), f2bf(wv4.z), f2bf(wv4.w) };
            *(bf16x4*)&Ws[r][c * 4] = wb;
        }
        #pragma unroll
        for (int i = 0; i < 2; ++i) {
            int cidx = i * 256 + tid;
            int r = cidx >> 2, c = cidx & 3;
            bf16x8 xv = *(const bf16x8*)(attn + (size_t)(m0 + r) * D_ + k0 + c * 8);
            *(bf16x8*)&Xs[r][c * 8] = xv;
        }
        __syncthreads();
        bf16x8 af[4], bfv[4];
        #pragma unroll
        for (int i = 0; i < 4; ++i) {
            af[i]  = *(const bf16x8*)&Ws[ar0 + 16 * i + l16][qq * 8];
            bfv[i] = *(const bf16x8*)&Xs[br0 + 16 * i + l16][qq * 8];
        }
        #pragma unroll
        for (int i = 0; i < 4; ++i)
            #pragma unroll
            for (int j = 0; j < 4; ++j)
                acc[i][j] = __builtin_amdgcn_mfma_f32_16x16x32_bf16(af[i], bfv[j], acc[i][j], 0, 0, 0);
        __syncthreads();
    }

    #pragma unroll
    for (int i = 0; i < 4; ++i) {
        int nb = n0 + ar0 + 16 * i + qq * 4;
        float4 b4 = *(const float4*)(bo + nb);
        #pragma unroll
        for (int j = 0; j < 4; ++j) {
            int m = m0 + br0 + 16 * j + l16;
            f32x4 c = acc[i][j];
            float4 ov = make_float4(c[0] + b4.x, c[1] + b4.y, c[2] + b4.z, c[3] + b4.w);
            *(float4*)&out[(size_t)m * D_ + nb] = ov;
        }
    }
}

// ---------------------------------------------------------------------------
extern "C" void kernel_launch(void* const* d_in, const int* in_sizes, int n_in,
                              void* d_out, int out_size, void* d_ws, size_t ws_size,
                              hipStream_t stream) {
    const float* q  = (const float*)d_in[0];
    const float* k  = (const float*)d_in[1];
    const float* v  = (const float*)d_in[2];
    const float* Wq = (const float*)d_in[3];
    const float* bq = (const float*)d_in[4];
    const float* Wk = (const float*)d_in[5];
    const float* bk = (const float*)d_in[6];
    const float* Wv = (const float*)d_in[7];
    const float* bv = (const float*)d_in[8];
    const float* Wo = (const float*)d_in[9];
    const float* bo = (const float*)d_in[10];
    const float* P  = (const float*)d_in[11];
    float* out = (float*)d_out;

    // ws: qh 8MB | qlo 8MB | kh 8MB | vht 8MB | attn 8MB (all bf16/short)
    char* ws = (char*)d_ws;
    short* qh   = (short*)(ws);
    short* qlo  = (short*)(ws + (size_t)8 * 1024 * 1024);
    short* kh   = (short*)(ws + (size_t)16 * 1024 * 1024);
    short* vht  = (short*)(ws + (size_t)24 * 1024 * 1024);
    short* attn = (short*)(ws + (size_t)32 * 1024 * 1024);

    proj_mfma<<<dim3(M_ / 128, D_ / 128, 3), 256, 0, stream>>>(
        q, k, v, Wq, bq, Wk, bk, Wv, bv, qh, qlo, kh, vht);
    attn_mfma<<<dim3(256), 512, 0, stream>>>(qh, qlo, kh, vht, P, attn);
    out_mfma<<<dim3(M_ / 128, D_ / 128), 256, 0, stream>>>(attn, Wo, bo, out);
}

// Round 8
// 434.407 us; speedup vs baseline: 8.8000x; 1.0012x over previous
//
#include <hip/hip_runtime.h>

#define D_  1024
#define H_  16
#define HD_ 64
#define L_  2048
#define B_  2
#define M_  (B_*L_)   // 4096 rows

typedef float f32x4  __attribute__((ext_vector_type(4)));
typedef short bf16x4 __attribute__((ext_vector_type(4)));
typedef short bf16x8 __attribute__((ext_vector_type(8)));

#define SRAW_PITCH 18   // dwords per l-row (72B): odd/2 stride -> conflict-free b64
#define VS_PITCH   36   // shorts per d-row (72B): same property

__device__ __forceinline__ float bf2f(short s) {
    return __uint_as_float(((unsigned int)(unsigned short)s) << 16);
}
__device__ __forceinline__ short f2bf(float f) {   // RNE
    unsigned u = __float_as_uint(f);
    unsigned r = (u + 0x7FFFu + ((u >> 16) & 1u)) >> 16;
    return (short)r;
}
// Raw barrier: orders all LDS ops (lgkmcnt(0) w/ "memory" clobber blocks IR-level
// motion of memory ops), but does NOT drain vmcnt -- in-flight global prefetches
// cross the barrier and are waited at first use (next iter). R4/R5 A/B showed
// this protocol gives identical results to __syncthreads (absmax matched).
__device__ __forceinline__ void block_sync() {
    asm volatile("s_waitcnt lgkmcnt(0)" ::: "memory");
    __builtin_amdgcn_sched_barrier(0);
    __builtin_amdgcn_s_barrier();
    __builtin_amdgcn_sched_barrier(0);
}

// ---------------------------------------------------------------------------
// Kernel 1: QKV projections via bf16 MFMA. 128x128 tile, K-step 32, 256 thr.
// z=0: q -> qh(hi)+qlo  [b][h][l][64]        (A=W rows n, B=X cols m: D[n][m])
// z=1: k -> kh          [b][h][l][64]        (same)
// z=2: v -> vht         [b][h][64][L]        (A=X rows m, B=W cols n: D[m][n])
// ---------------------------------------------------------------------------
__global__ __launch_bounds__(256) void proj_mfma(
    const float* __restrict__ q, const float* __restrict__ k, const float* __restrict__ v,
    const float* __restrict__ Wq, const float* __restrict__ bq,
    const float* __restrict__ Wk, const float* __restrict__ bk,
    const float* __restrict__ Wv, const float* __restrict__ bv,
    short* __restrict__ qh, short* __restrict__ qlo,
    short* __restrict__ kh, short* __restrict__ vht)
{
    const int z = blockIdx.z;
    const float* X    = (z == 0) ? q  : (z == 1) ? k  : v;
    const float* W    = (z == 0) ? Wq : (z == 1) ? Wk : Wv;
    const float* bias = (z == 0) ? bq : (z == 1) ? bk : bv;

    __shared__ short Ws[128][40];
    __shared__ short Xs[128][40];

    const int tid  = threadIdx.x;
    const int w    = tid >> 6, lane = tid & 63;
    const int l16  = lane & 15, qq = lane >> 4;
    const int m0   = blockIdx.x * 128;
    const int n0   = blockIdx.y * 128;
    const int ar0  = 64 * (w & 1);
    const int br0  = 64 * (w >> 1);

    f32x4 acc[4][4] = {};

    for (int k0 = 0; k0 < D_; k0 += 32) {
        #pragma unroll
        for (int i = 0; i < 4; ++i) {
            int fidx = i * 256 + tid;
            int r = fidx >> 3, c = fidx & 7;
            float4 wv4 = *(const float4*)(W + (size_t)(n0 + r) * D_ + k0 + c * 4);
            float4 xv4 = *(const float4*)(X + (size_t)(m0 + r) * D_ + k0 + c * 4);
            bf16x4 wb = { f2bf(wv4.x), f2bf(wv4.y), f2bf(wv4.z), f2bf(wv4.w) };
            bf16x4 xb = { f2bf(xv4.x), f2bf(xv4.y), f2bf(xv4.z), f2bf(xv4.w) };
            *(bf16x4*)&Ws[r][c * 4] = wb;
            *(bf16x4*)&Xs[r][c * 4] = xb;
        }
        __syncthreads();
        bf16x8 af[4], bfv[4];
        #pragma unroll
        for (int i = 0; i < 4; ++i) {
            // z<2: A=W (rows n), B=X (cols m).  z==2: A=X (rows m), B=W (cols n).
            const short* Ab = (z < 2) ? &Ws[ar0 + 16 * i + l16][qq * 8]
                                      : &Xs[ar0 + 16 * i + l16][qq * 8];
            const short* Bb = (z < 2) ? &Xs[br0 + 16 * i + l16][qq * 8]
                                      : &Ws[br0 + 16 * i + l16][qq * 8];
            af[i]  = *(const bf16x8*)Ab;
            bfv[i] = *(const bf16x8*)Bb;
        }
        #pragma unroll
        for (int i = 0; i < 4; ++i)
            #pragma unroll
            for (int j = 0; j < 4; ++j)
                acc[i][j] = __builtin_amdgcn_mfma_f32_16x16x32_bf16(af[i], bfv[j], acc[i][j], 0, 0, 0);
        __syncthreads();
    }

    if (z < 2) {
        #pragma unroll
        for (int i = 0; i < 4; ++i) {
            int nb = n0 + ar0 + 16 * i + qq * 4;
            float4 b4 = *(const float4*)(bias + nb);
            int h = nb >> 6, hd = nb & 63;
            #pragma unroll
            for (int j = 0; j < 4; ++j) {
                int m = m0 + br0 + 16 * j + l16;
                int bb = m >> 11, l = m & (L_ - 1);
                size_t o = ((((size_t)bb * H_ + h) * L_) + l) * HD_ + hd;
                f32x4 c = acc[i][j];
                float v0 = c[0] + b4.x, v1 = c[1] + b4.y, v2 = c[2] + b4.z, v3 = c[3] + b4.w;
                bf16x4 hi = { f2bf(v0), f2bf(v1), f2bf(v2), f2bf(v3) };
                if (z == 0) {
                    *(bf16x4*)&qh[o] = hi;
                    bf16x4 lo = { f2bf(v0 - bf2f(hi[0])), f2bf(v1 - bf2f(hi[1])),
                                  f2bf(v2 - bf2f(hi[2])), f2bf(v3 - bf2f(hi[3])) };
                    *(bf16x4*)&qlo[o] = lo;
                } else {
                    *(bf16x4*)&kh[o] = hi;
                }
            }
        }
    } else {
        // D[m][n]: rows m = m0+ar0+16i+4qq+r ; cols n = n0+br0+16j+l16
        #pragma unroll
        for (int i = 0; i < 4; ++i) {
            int mb = m0 + ar0 + 16 * i + qq * 4;
            int bb = mb >> 11, lb = mb & (L_ - 1);
            #pragma unroll
            for (int j = 0; j < 4; ++j) {
                int n = n0 + br0 + 16 * j + l16;
                int h = n >> 6, hd = n & 63;
                float bn = bias[n];
                size_t o = (((size_t)bb * H_ + h) * HD_ + hd) * (size_t)L_ + lb;
                f32x4 c = acc[i][j];
                bf16x4 ov = { f2bf(c[0] + bn), f2bf(c[1] + bn), f2bf(c[2] + bn), f2bf(c[3] + bn) };
                *(bf16x4*)&vht[o] = ov;
            }
        }
    }
}

// ---------------------------------------------------------------------------
// Kernel 2: fused talking-heads attention. 512 thr (8 waves), l-tile 16,
// m-tile 16, all heads per block. Wave w: heads/g {2w, 2w+1}.
// R8: raw barrier (no vmcnt drain -> prefetches stay in flight across it) +
// deferred-max softmax (pf = exp(sx - m_old); single rescale at body end).
// ---------------------------------------------------------------------------
__global__ __launch_bounds__(512, 2) void attn_mfma(
    const short* __restrict__ qh, const short* __restrict__ qlo,
    const short* __restrict__ kh, const short* __restrict__ vht,
    const float* __restrict__ P, short* __restrict__ attn_out)
{
    __shared__ __align__(16) float Sraw0[16 * 16 * SRAW_PITCH];   // 18.4 KB
    __shared__ __align__(16) float Sraw1[16 * 16 * SRAW_PITCH];   // 18.4 KB
    __shared__ __align__(16) short Vslab[8][2 * 64 * VS_PITCH];   // 73.7 KB
    __shared__ float PmS[256];

    const int tid  = threadIdx.x;
    const int n    = blockIdx.x;
    const int b    = (n >> 2) & 1;                        // XCD swizzle
    const int l0   = ((n >> 3) * 4 + (n & 3)) * 16;
    const int w    = tid >> 6, lane = tid & 63;
    const int l16  = lane & 15, qq = lane >> 4;
    const size_t hb = (size_t)b * H_;

    // ---- Q frags (persistent)
    bf16x8 qf[2][2][2];
    #pragma unroll
    for (int hh = 0; hh < 2; ++hh)
        #pragma unroll
        for (int kc = 0; kc < 2; ++kc) {
            size_t off = ((hb + 2 * w + hh) * L_ + l0 + l16) * HD_ + kc * 32 + qq * 8;
            qf[hh][kc][0] = *(const bf16x8*)(qh  + off);
            qf[hh][kc][1] = *(const bf16x8*)(qlo + off);
        }

    // V^T staging mapping (i: row = i*32 + (lane>>1); gi = row>>6, d = row&63; vc = lane&1)
    int vgi_[4], vd_[4];
    const int vc = lane & 1;
    #pragma unroll
    for (int i = 0; i < 4; ++i) {
        int vrow = i * 32 + (lane >> 1);
        vgi_[i] = vrow >> 6;
        vd_[i]  = vrow & 63;
    }
    int vwoff[4];
    #pragma unroll
    for (int i = 0; i < 4; ++i)
        vwoff[i] = vgi_[i] * (64 * VS_PITCH) + vd_[i] * VS_PITCH + vc * 8;

    // ---- double-buffered K/V registers: A = even tiles, B = odd tiles
    bf16x8 kA[2][2], kB[2][2], vA[4], vB[4];
    #pragma unroll
    for (int hh = 0; hh < 2; ++hh)
        #pragma unroll
        for (int kc = 0; kc < 2; ++kc) {
            kA[hh][kc] = *(const bf16x8*)(kh + ((hb + 2 * w + hh) * L_ + 0  + l16) * HD_ + kc * 32 + qq * 8);
            kB[hh][kc] = *(const bf16x8*)(kh + ((hb + 2 * w + hh) * L_ + 16 + l16) * HD_ + kc * 32 + qq * 8);
        }
    #pragma unroll
    for (int i = 0; i < 4; ++i) {
        vA[i] = *(const bf16x8*)(vht + ((hb + 2 * w + vgi_[i]) * HD_ + vd_[i]) * (size_t)L_ + 0  + vc * 8);
        vB[i] = *(const bf16x8*)(vht + ((hb + 2 * w + vgi_[i]) * HD_ + vd_[i]) * (size_t)L_ + 16 + vc * 8);
    }

    if (tid < 256) PmS[tid] = P[tid] * 0.125f;            // fold 1/sqrt(64)

    f32x4 acc[2][4];
    #pragma unroll
    for (int dt = 0; dt < 4; ++dt) { acc[0][dt] = (f32x4){0.f,0.f,0.f,0.f}; acc[1][dt] = (f32x4){0.f,0.f,0.f,0.f}; }
    // deferred-max: m_run init 0 (mixed logits ~N(0,16); worst first-tile
    // delta ~24 -> exp(24)=2.6e10, far inside f32 range)
    float mrun0 = 0.f, mrun1 = 0.f, srun0 = 0.f, srun1 = 0.f;

    // QK^T: D[m][l], col=l16, rows m=qq*4+j.  Writes as 2x b64 (rows 72B).
    auto qkt = [&](bf16x8 (&kr)[2][2], float* sb) {
        #pragma unroll
        for (int hh = 0; hh < 2; ++hh) {
            f32x4 s = (f32x4){0.f,0.f,0.f,0.f};
            s = __builtin_amdgcn_mfma_f32_16x16x32_bf16(kr[hh][0], qf[hh][0][0], s, 0, 0, 0);
            s = __builtin_amdgcn_mfma_f32_16x16x32_bf16(kr[hh][0], qf[hh][0][1], s, 0, 0, 0);
            s = __builtin_amdgcn_mfma_f32_16x16x32_bf16(kr[hh][1], qf[hh][1][0], s, 0, 0, 0);
            s = __builtin_amdgcn_mfma_f32_16x16x32_bf16(kr[hh][1], qf[hh][1][1], s, 0, 0, 0);
            float* sp = sb + ((2 * w + hh) * 16 + l16) * SRAW_PITCH + qq * 4;
            *(float2*)sp       = make_float2(s[0], s[1]);
            *(float2*)(sp + 2) = make_float2(s[2], s[3]);
        }
    };

    // prologue: QK^T(tile 0) -> Sraw0, publish
    qkt(kA, Sraw0);
    block_sync();

    float pw0[16], pw1[16];
    #pragma unroll
    for (int h = 0; h < 16; ++h) {
        pw0[h] = PmS[h * 16 + 2 * w];
        pw1[h] = PmS[h * 16 + 2 * w + 1];
    }

    // body: stage V(t); prefetch(t+2); mix(t); pf=exp(sx-m_old); PV(t);
    // QK^T(t+1)->other buf; end-of-body rescale; raw barrier.
    auto body = [&](float* sb, float* sbo, bf16x8 (&vstage)[4], bf16x8 (&kqk)[2][2],
                    bf16x8 (&kld)[2][2], bf16x8 (&vld)[4], int tnext) {
        // 1. stage V(t) into per-wave slab (2x b64 per 16B chunk)
        #pragma unroll
        for (int i = 0; i < 4; ++i) {
            bf16x4 wlo = { vstage[i][0], vstage[i][1], vstage[i][2], vstage[i][3] };
            bf16x4 whi = { vstage[i][4], vstage[i][5], vstage[i][6], vstage[i][7] };
            *(bf16x4*)&Vslab[w][vwoff[i]]     = wlo;
            *(bf16x4*)&Vslab[w][vwoff[i] + 4] = whi;
        }
        // 2. prefetch tile tnext (global -> regs; in flight across the raw barrier,
        //    waited by compiler vmcnt at first use ~1 full iter later)
        {
            const int mn = tnext * 16;
            #pragma unroll
            for (int hh = 0; hh < 2; ++hh)
                #pragma unroll
                for (int kc = 0; kc < 2; ++kc)
                    kld[hh][kc] = *(const bf16x8*)(kh + ((hb + 2 * w + hh) * L_ + mn + l16) * HD_ + kc * 32 + qq * 8);
            #pragma unroll
            for (int i = 0; i < 4; ++i)
                vld[i] = *(const bf16x8*)(vht + ((hb + 2 * w + vgi_[i]) * HD_ + vd_[i]) * (size_t)L_ + mn + vc * 8);
        }
        // 3. talking-heads mix from sb (2x b64 per h, conflict-free pitch)
        float sx0[4] = {0.f,0.f,0.f,0.f}, sx1[4] = {0.f,0.f,0.f,0.f};
        #pragma unroll
        for (int h = 0; h < 16; ++h) {
            const float* sp = sb + (h * 16 + l16) * SRAW_PITCH + qq * 4;
            float2 ca = *(const float2*)sp;
            float2 cb = *(const float2*)(sp + 2);
            sx0[0] += pw0[h] * ca.x; sx0[1] += pw0[h] * ca.y;
            sx0[2] += pw0[h] * cb.x; sx0[3] += pw0[h] * cb.y;
            sx1[0] += pw1[h] * ca.x; sx1[1] += pw1[h] * ca.y;
            sx1[2] += pw1[h] * cb.x; sx1[3] += pw1[h] * cb.y;
        }
        // 4. deferred-max: pf referenced to m_old -> PV can start immediately;
        //    max/sum reduces run in parallel with PV (not on its critical path)
        float e00 = __expf(sx0[0] - mrun0), e01 = __expf(sx0[1] - mrun0);
        float e02 = __expf(sx0[2] - mrun0), e03 = __expf(sx0[3] - mrun0);
        float e10 = __expf(sx1[0] - mrun1), e11 = __expf(sx1[1] - mrun1);
        float e12 = __expf(sx1[2] - mrun1), e13 = __expf(sx1[3] - mrun1);
        bf16x4 pf0 = { f2bf(e00), f2bf(e01), f2bf(e02), f2bf(e03) };
        bf16x4 pf1 = { f2bf(e10), f2bf(e11), f2bf(e12), f2bf(e13) };
        float t0 = fmaxf(fmaxf(sx0[0], sx0[1]), fmaxf(sx0[2], sx0[3]));
        float t1 = fmaxf(fmaxf(sx1[0], sx1[1]), fmaxf(sx1[2], sx1[3]));
        t0 = fmaxf(t0, __shfl_xor(t0, 16)); t0 = fmaxf(t0, __shfl_xor(t0, 32));
        t1 = fmaxf(t1, __shfl_xor(t1, 16)); t1 = fmaxf(t1, __shfl_xor(t1, 32));
        float ps0 = e00 + e01 + e02 + e03, ps1 = e10 + e11 + e12 + e13;
        ps0 += __shfl_xor(ps0, 16); ps0 += __shfl_xor(ps0, 32);
        ps1 += __shfl_xor(ps1, 16); ps1 += __shfl_xor(ps1, 32);
        // 5. PV: A = V^T rows d from slab (b64), B = pf.  D[d][l], col=l16.
        //    Contributions use m_old reference; rescale below converts everything.
        #pragma unroll
        for (int i = 0; i < 2; ++i) {
            bf16x4 pf = i ? pf1 : pf0;
            #pragma unroll
            for (int dt = 0; dt < 4; ++dt) {
                bf16x4 afr = *(const bf16x4*)&Vslab[w][i * (64 * VS_PITCH) + (dt * 16 + l16) * VS_PITCH + qq * 4];
                acc[i][dt] = __builtin_amdgcn_mfma_f32_16x16x16bf16_1k(afr, pf, acc[i][dt], 0, 0, 0);
            }
        }
        // 6. QK^T(t+1) -> other Sraw buffer
        qkt(kqk, sbo);
        // 7. end-of-body rescale to the new running max
        float mnew0 = fmaxf(mrun0, t0), mnew1 = fmaxf(mrun1, t1);
        float corr0 = __expf(mrun0 - mnew0), corr1 = __expf(mrun1 - mnew1);
        srun0 = (srun0 + ps0) * corr0; srun1 = (srun1 + ps1) * corr1;
        acc[0][0] *= corr0; acc[0][1] *= corr0; acc[0][2] *= corr0; acc[0][3] *= corr0;
        acc[1][0] *= corr1; acc[1][1] *= corr1; acc[1][2] *= corr1; acc[1][3] *= corr1;
        mrun0 = mnew0; mrun1 = mnew1;
        block_sync();   // raw: LDS ordered, global prefetches stay in flight
    };

    for (int itp = 0; itp < 64; ++itp) {
        const int t0 = 2 * itp;
        body(Sraw0, Sraw1, vA, kB, kA, vA, (t0 + 2) & 127);   // even tile t0
        body(Sraw1, Sraw0, vB, kA, kB, vB, (t0 + 3) & 127);   // odd tile t0+1
    }

    // epilogue: D[d][l] -> out[b][l][g*64 + d]
    float inv0 = 1.f / srun0, inv1 = 1.f / srun1;
    #pragma unroll
    for (int i = 0; i < 2; ++i) {
        float inv = i ? inv1 : inv0;
        #pragma unroll
        for (int dt = 0; dt < 4; ++dt) {
            f32x4 a = acc[i][dt];
            bf16x4 ov = { f2bf(a[0] * inv), f2bf(a[1] * inv), f2bf(a[2] * inv), f2bf(a[3] * inv) };
            *(bf16x4*)(attn_out + ((size_t)(b * L_ + l0 + l16)) * D_ + (2 * w + i) * 64 + dt * 16 + qq * 4) = ov;
        }
    }
}

// ---------------------------------------------------------------------------
// Kernel 3: output projection (attn bf16 @ Wo^T + bo) -> f32, MFMA.
// ---------------------------------------------------------------------------
__global__ __launch_bounds__(256) void out_mfma(
    const short* __restrict__ attn, const float* __restrict__ Wo,
    const float* __restrict__ bo, float* __restrict__ out)
{
    __shared__ short Ws[128][40];
    __shared__ short Xs[128][40];

    const int tid = threadIdx.x;
    const int w = tid >> 6, lane = tid & 63;
    const int l16 = lane & 15, qq = lane >> 4;
    const int m0 = blockIdx.x * 128;
    const int n0 = blockIdx.y * 128;
    const int ar0 = 64 * (w & 1);
    const int br0 = 64 * (w >> 1);

    f32x4 acc[4][4] = {};

    for (int k0 = 0; k0 < D_; k0 += 32) {
        #pragma unroll
        for (int i = 0; i < 4; ++i) {
            int fidx = i * 256 + tid;
            int r = fidx >> 3, c = fidx & 7;
            float4 wv4 = *(const float4*)(Wo + (size_t)(n0 + r) * D_ + k0 + c * 4);
            bf16x4 wb = { f2bf(wv4.x), f2bf(wv4.y), f2bf(wv4.z), f2bf(wv4.w) };
            *(bf16x4*)&Ws[r][c * 4] = wb;
        }
        #pragma unroll
        for (int i = 0; i < 2; ++i) {
            int cidx = i * 256 + tid;
            int r = cidx >> 2, c = cidx & 3;
            bf16x8 xv = *(const bf16x8*)(attn + (size_t)(m0 + r) * D_ + k0 + c * 8);
            *(bf16x8*)&Xs[r][c * 8] = xv;
        }
        __syncthreads();
        bf16x8 af[4], bfv[4];
        #pragma unroll
        for (int i = 0; i < 4; ++i) {
            af[i]  = *(const bf16x8*)&Ws[ar0 + 16 * i + l16][qq * 8];
            bfv[i] = *(const bf16x8*)&Xs[br0 + 16 * i + l16][qq * 8];
        }
        #pragma unroll
        for (int i = 0; i < 4; ++i)
            #pragma unroll
            for (int j = 0; j < 4; ++j)
                acc[i][j] = __builtin_amdgcn_mfma_f32_16x16x32_bf16(af[i], bfv[j], acc[i][j], 0, 0, 0);
        __syncthreads();
    }

    #pragma unroll
    for (int i = 0; i < 4; ++i) {
        int nb = n0 + ar0 + 16 * i + qq * 4;
        float4 b4 = *(const float4*)(bo + nb);
        #pragma unroll
        for (int j = 0; j < 4; ++j) {
            int m = m0 + br0 + 16 * j + l16;
            f32x4 c = acc[i][j];
            float4 ov = make_float4(c[0] + b4.x, c[1] + b4.y, c[2] + b4.z, c[3] + b4.w);
            *(float4*)&out[(size_t)m * D_ + nb] = ov;
        }
    }
}

// ---------------------------------------------------------------------------
extern "C" void kernel_launch(void* const* d_in, const int* in_sizes, int n_in,
                              void* d_out, int out_size, void* d_ws, size_t ws_size,
                              hipStream_t stream) {
    const float* q  = (const float*)d_in[0];
    const float* k  = (const float*)d_in[1];
    const float* v  = (const float*)d_in[2];
    const float* Wq = (const float*)d_in[3];
    const float* bq = (const float*)d_in[4];
    const float* Wk = (const float*)d_in[5];
    const float* bk = (const float*)d_in[6];
    const float* Wv = (const float*)d_in[7];
    const float* bv = (const float*)d_in[8];
    const float* Wo = (const float*)d_in[9];
    const float* bo = (const float*)d_in[10];
    const float* P  = (const float*)d_in[11];
    float* out = (float*)d_out;

    // ws: qh 8MB | qlo 8MB | kh 8MB | vht 8MB | attn 8MB (all bf16/short)
    char* ws = (char*)d_ws;
    short* qh   = (short*)(ws);
    short* qlo  = (short*)(ws + (size_t)8 * 1024 * 1024);
    short* kh   = (short*)(ws + (size_t)16 * 1024 * 1024);
    short* vht  = (short*)(ws + (size_t)24 * 1024 * 1024);
    short* attn = (short*)(ws + (size_t)32 * 1024 * 1024);

    proj_mfma<<<dim3(M_ / 128, D_ / 128, 3), 256, 0, stream>>>(
        q, k, v, Wq, bq, Wk, bk, Wv, bv, qh, qlo, kh, vht);
    attn_mfma<<<dim3(256), 512, 0, stream>>>(qh, qlo, kh, vht, P, attn);
    out_mfma<<<dim3(M_ / 128, D_ / 128), 256, 0, stream>>>(attn, Wo, bo, out);
}

// Round 9
// 408.127 us; speedup vs baseline: 9.3666x; 1.0644x over previous
//
#include <hip/hip_runtime.h>

#define D_  1024
#define H_  16
#define HD_ 64
#define L_  2048
#define B_  2
#define M_  (B_*L_)   // 4096 rows

typedef float f32x4  __attribute__((ext_vector_type(4)));
typedef short bf16x4 __attribute__((ext_vector_type(4)));
typedef short bf16x8 __attribute__((ext_vector_type(8)));

#define SRAW_PITCH 18   // f32 per l-row (72B): conflict-free b64/scalar patterns
#define SRAW_SLAB  (16 * SRAW_PITCH)   // 288 f32 per h (or m) slab
#define VS_PITCH   36   // shorts per d-row (72B)

__device__ __forceinline__ float bf2f(short s) {
    return __uint_as_float(((unsigned int)(unsigned short)s) << 16);
}
__device__ __forceinline__ short f2bf(float f) {   // RNE
    unsigned u = __float_as_uint(f);
    unsigned r = (u + 0x7FFFu + ((u >> 16) & 1u)) >> 16;
    return (short)r;
}
// Raw barrier: orders LDS (lgkmcnt(0) + "memory" clobber), does NOT drain vmcnt.
// Verified equivalent to __syncthreads for this kernel's protocol (R4==R5 absmax).
__device__ __forceinline__ void block_sync() {
    asm volatile("s_waitcnt lgkmcnt(0)" ::: "memory");
    __builtin_amdgcn_sched_barrier(0);
    __builtin_amdgcn_s_barrier();
    __builtin_amdgcn_sched_barrier(0);
}

// ---------------------------------------------------------------------------
// Kernel 1: QKV projections via bf16 MFMA. 128x128 tile, K-step 32, 256 thr.
// z=0: q -> qh(hi)+qlo  [b][h][l][64]        (A=W rows n, B=X cols m: D[n][m])
// z=1: k -> kh          [b][h][l][64]        (same)
// z=2: v -> vht         [b][h][64][L]        (A=X rows m, B=W cols n: D[m][n])
// ---------------------------------------------------------------------------
__global__ __launch_bounds__(256) void proj_mfma(
    const float* __restrict__ q, const float* __restrict__ k, const float* __restrict__ v,
    const float* __restrict__ Wq, const float* __restrict__ bq,
    const float* __restrict__ Wk, const float* __restrict__ bk,
    const float* __restrict__ Wv, const float* __restrict__ bv,
    short* __restrict__ qh, short* __restrict__ qlo,
    short* __restrict__ kh, short* __restrict__ vht)
{
    const int z = blockIdx.z;
    const float* X    = (z == 0) ? q  : (z == 1) ? k  : v;
    const float* W    = (z == 0) ? Wq : (z == 1) ? Wk : Wv;
    const float* bias = (z == 0) ? bq : (z == 1) ? bk : bv;

    __shared__ short Ws[128][40];
    __shared__ short Xs[128][40];

    const int tid  = threadIdx.x;
    const int w    = tid >> 6, lane = tid & 63;
    const int l16  = lane & 15, qq = lane >> 4;
    const int m0   = blockIdx.x * 128;
    const int n0   = blockIdx.y * 128;
    const int ar0  = 64 * (w & 1);
    const int br0  = 64 * (w >> 1);

    f32x4 acc[4][4] = {};

    for (int k0 = 0; k0 < D_; k0 += 32) {
        #pragma unroll
        for (int i = 0; i < 4; ++i) {
            int fidx = i * 256 + tid;
            int r = fidx >> 3, c = fidx & 7;
            float4 wv4 = *(const float4*)(W + (size_t)(n0 + r) * D_ + k0 + c * 4);
            float4 xv4 = *(const float4*)(X + (size_t)(m0 + r) * D_ + k0 + c * 4);
            bf16x4 wb = { f2bf(wv4.x), f2bf(wv4.y), f2bf(wv4.z), f2bf(wv4.w) };
            bf16x4 xb = { f2bf(xv4.x), f2bf(xv4.y), f2bf(xv4.z), f2bf(xv4.w) };
            *(bf16x4*)&Ws[r][c * 4] = wb;
            *(bf16x4*)&Xs[r][c * 4] = xb;
        }
        __syncthreads();
        bf16x8 af[4], bfv[4];
        #pragma unroll
        for (int i = 0; i < 4; ++i) {
            // z<2: A=W (rows n), B=X (cols m).  z==2: A=X (rows m), B=W (cols n).
            const short* Ab = (z < 2) ? &Ws[ar0 + 16 * i + l16][qq * 8]
                                      : &Xs[ar0 + 16 * i + l16][qq * 8];
            const short* Bb = (z < 2) ? &Xs[br0 + 16 * i + l16][qq * 8]
                                      : &Ws[br0 + 16 * i + l16][qq * 8];
            af[i]  = *(const bf16x8*)Ab;
            bfv[i] = *(const bf16x8*)Bb;
        }
        #pragma unroll
        for (int i = 0; i < 4; ++i)
            #pragma unroll
            for (int j = 0; j < 4; ++j)
                acc[i][j] = __builtin_amdgcn_mfma_f32_16x16x32_bf16(af[i], bfv[j], acc[i][j], 0, 0, 0);
        __syncthreads();
    }

    if (z < 2) {
        #pragma unroll
        for (int i = 0; i < 4; ++i) {
            int nb = n0 + ar0 + 16 * i + qq * 4;
            float4 b4 = *(const float4*)(bias + nb);
            int h = nb >> 6, hd = nb & 63;
            #pragma unroll
            for (int j = 0; j < 4; ++j) {
                int m = m0 + br0 + 16 * j + l16;
                int bb = m >> 11, l = m & (L_ - 1);
                size_t o = ((((size_t)bb * H_ + h) * L_) + l) * HD_ + hd;
                f32x4 c = acc[i][j];
                float v0 = c[0] + b4.x, v1 = c[1] + b4.y, v2 = c[2] + b4.z, v3 = c[3] + b4.w;
                bf16x4 hi = { f2bf(v0), f2bf(v1), f2bf(v2), f2bf(v3) };
                if (z == 0) {
                    *(bf16x4*)&qh[o] = hi;
                    bf16x4 lo = { f2bf(v0 - bf2f(hi[0])), f2bf(v1 - bf2f(hi[1])),
                                  f2bf(v2 - bf2f(hi[2])), f2bf(v3 - bf2f(hi[3])) };
                    *(bf16x4*)&qlo[o] = lo;
                } else {
                    *(bf16x4*)&kh[o] = hi;
                }
            }
        }
    } else {
        // D[m][n]: rows m = m0+ar0+16i+4qq+r ; cols n = n0+br0+16j+l16
        #pragma unroll
        for (int i = 0; i < 4; ++i) {
            int mb = m0 + ar0 + 16 * i + qq * 4;
            int bb = mb >> 11, lb = mb & (L_ - 1);
            #pragma unroll
            for (int j = 0; j < 4; ++j) {
                int n = n0 + br0 + 16 * j + l16;
                int h = n >> 6, hd = n & 63;
                float bn = bias[n];
                size_t o = (((size_t)bb * H_ + h) * HD_ + hd) * (size_t)L_ + lb;
                f32x4 c = acc[i][j];
                bf16x4 ov = { f2bf(c[0] + bn), f2bf(c[1] + bn), f2bf(c[2] + bn), f2bf(c[3] + bn) };
                *(bf16x4*)&vht[o] = ov;
            }
        }
    }
}

// ---------------------------------------------------------------------------
// Kernel 2: fused talking-heads attention. 512 thr (8 waves), l-tile 16,
// m-tile 16, all heads per block. Wave w: heads/g {2w, 2w+1}, m-inst {2w,2w+1}.
// R9: talking-heads mix via MFMA (A = P^T broadcast hi/lo, B = scalar-gathered
// S hi/lo, D2 -> Smix[m][l][g]) -- removes 128 VALU FMAs + 32 fat b64 LDS
// reads per wave per body. Softmax/PV layouts unchanged.
// ---------------------------------------------------------------------------
__global__ __launch_bounds__(512, 2) void attn_mfma(
    const short* __restrict__ qh, const short* __restrict__ qlo,
    const short* __restrict__ kh, const short* __restrict__ vht,
    const float* __restrict__ P, short* __restrict__ attn_out)
{
    __shared__ __align__(16) float Sraw0[16 * SRAW_SLAB];         // [h][l][18] 18.4 KB
    __shared__ __align__(16) float Sraw1[16 * SRAW_SLAB];         // 18.4 KB
    __shared__ __align__(16) float Smix[16 * SRAW_SLAB];          // [m][l][18] (g fast) 18.4 KB
    __shared__ __align__(16) short Vslab[8][2 * 64 * VS_PITCH];   // 73.7 KB
    __shared__ float PmS[256];

    const int tid  = threadIdx.x;
    const int n    = blockIdx.x;
    const int b    = (n >> 2) & 1;                        // XCD swizzle
    const int l0   = ((n >> 3) * 4 + (n & 3)) * 16;
    const int w    = tid >> 6, lane = tid & 63;
    const int l16  = lane & 15, qq = lane >> 4;
    const size_t hb = (size_t)b * H_;

    // ---- Q frags (persistent)
    bf16x8 qf[2][2][2];
    #pragma unroll
    for (int hh = 0; hh < 2; ++hh)
        #pragma unroll
        for (int kc = 0; kc < 2; ++kc) {
            size_t off = ((hb + 2 * w + hh) * L_ + l0 + l16) * HD_ + kc * 32 + qq * 8;
            qf[hh][kc][0] = *(const bf16x8*)(qh  + off);
            qf[hh][kc][1] = *(const bf16x8*)(qlo + off);
        }

    // V^T staging mapping (i: row = i*32 + (lane>>1); gi = row>>6, d = row&63; vc = lane&1)
    int vgi_[4], vd_[4];
    const int vc = lane & 1;
    #pragma unroll
    for (int i = 0; i < 4; ++i) {
        int vrow = i * 32 + (lane >> 1);
        vgi_[i] = vrow >> 6;
        vd_[i]  = vrow & 63;
    }
    int vwoff[4];
    #pragma unroll
    for (int i = 0; i < 4; ++i)
        vwoff[i] = vgi_[i] * (64 * VS_PITCH) + vd_[i] * VS_PITCH + vc * 8;

    // ---- double-buffered K/V registers: A = even tiles, B = odd tiles
    bf16x8 kA[2][2], kB[2][2], vA[4], vB[4];
    #pragma unroll
    for (int hh = 0; hh < 2; ++hh)
        #pragma unroll
        for (int kc = 0; kc < 2; ++kc) {
            kA[hh][kc] = *(const bf16x8*)(kh + ((hb + 2 * w + hh) * L_ + 0  + l16) * HD_ + kc * 32 + qq * 8);
            kB[hh][kc] = *(const bf16x8*)(kh + ((hb + 2 * w + hh) * L_ + 16 + l16) * HD_ + kc * 32 + qq * 8);
        }
    #pragma unroll
    for (int i = 0; i < 4; ++i) {
        vA[i] = *(const bf16x8*)(vht + ((hb + 2 * w + vgi_[i]) * HD_ + vd_[i]) * (size_t)L_ + 0  + vc * 8);
        vB[i] = *(const bf16x8*)(vht + ((hb + 2 * w + vgi_[i]) * HD_ + vd_[i]) * (size_t)L_ + 16 + vc * 8);
    }

    if (tid < 256) PmS[tid] = P[tid] * 0.125f;            // fold 1/sqrt(64)

    f32x4 acc[2][4];
    #pragma unroll
    for (int dt = 0; dt < 4; ++dt) { acc[0][dt] = (f32x4){0.f,0.f,0.f,0.f}; acc[1][dt] = (f32x4){0.f,0.f,0.f,0.f}; }
    // deferred-max running state (m_run init 0; mixed logits ~N(0,16))
    float mrun0 = 0.f, mrun1 = 0.f, srun0 = 0.f, srun1 = 0.f;

    // QK^T: D[m][l], col=l16, rows m=qq*4+j.  Writes 2x b64 per head slab.
    auto qkt = [&](bf16x8 (&kr)[2][2], float* sb) {
        #pragma unroll
        for (int hh = 0; hh < 2; ++hh) {
            f32x4 s = (f32x4){0.f,0.f,0.f,0.f};
            s = __builtin_amdgcn_mfma_f32_16x16x32_bf16(kr[hh][0], qf[hh][0][0], s, 0, 0, 0);
            s = __builtin_amdgcn_mfma_f32_16x16x32_bf16(kr[hh][0], qf[hh][0][1], s, 0, 0, 0);
            s = __builtin_amdgcn_mfma_f32_16x16x32_bf16(kr[hh][1], qf[hh][1][0], s, 0, 0, 0);
            s = __builtin_amdgcn_mfma_f32_16x16x32_bf16(kr[hh][1], qf[hh][1][1], s, 0, 0, 0);
            float* sp = sb + ((2 * w + hh) * 16 + l16) * SRAW_PITCH + qq * 4;
            *(float2*)sp       = make_float2(s[0], s[1]);
            *(float2*)(sp + 2) = make_float2(s[2], s[3]);
        }
    };

    // prologue: QK^T(tile 0) -> Sraw0, publish (also makes PmS visible)
    qkt(kA, Sraw0);
    block_sync();

    // ---- mix A-operand: P^T hi/lo broadcast fragment.
    // A[g][h]: row g = l16 (lane&15), k h = qq*4+j  -> PAhi[j] = PmS[(qq*4+j)*16 + l16]
    bf16x4 PAhi, PAlo;
    {
        float p0 = PmS[(qq * 4 + 0) * 16 + l16];
        float p1 = PmS[(qq * 4 + 1) * 16 + l16];
        float p2 = PmS[(qq * 4 + 2) * 16 + l16];
        float p3 = PmS[(qq * 4 + 3) * 16 + l16];
        PAhi = (bf16x4){ f2bf(p0), f2bf(p1), f2bf(p2), f2bf(p3) };
        PAlo = (bf16x4){ f2bf(p0 - bf2f(PAhi[0])), f2bf(p1 - bf2f(PAhi[1])),
                         f2bf(p2 - bf2f(PAhi[2])), f2bf(p3 - bf2f(PAhi[3])) };
    }

    // mix via MFMA for this wave's two m-instances (m = 2w, 2w+1):
    // B[h][l]: lane (col=l16, k h=qq*4+j) = Sraw[h][l16][m] (scalar gather, f32->hi/lo)
    // D2[g][l]: lane (col=l16, row g=qq*4+j) -> Smix[m][l][g]
    auto mixmfma = [&](const float* sb) {
        #pragma unroll
        for (int mi = 0; mi < 2; ++mi) {
            const int m = 2 * w + mi;
            float sv0 = sb[(qq * 4 + 0) * SRAW_SLAB + l16 * SRAW_PITCH + m];
            float sv1 = sb[(qq * 4 + 1) * SRAW_SLAB + l16 * SRAW_PITCH + m];
            float sv2 = sb[(qq * 4 + 2) * SRAW_SLAB + l16 * SRAW_PITCH + m];
            float sv3 = sb[(qq * 4 + 3) * SRAW_SLAB + l16 * SRAW_PITCH + m];
            bf16x4 bhi = { f2bf(sv0), f2bf(sv1), f2bf(sv2), f2bf(sv3) };
            bf16x4 blo = { f2bf(sv0 - bf2f(bhi[0])), f2bf(sv1 - bf2f(bhi[1])),
                           f2bf(sv2 - bf2f(bhi[2])), f2bf(sv3 - bf2f(bhi[3])) };
            f32x4 c = (f32x4){0.f, 0.f, 0.f, 0.f};
            c = __builtin_amdgcn_mfma_f32_16x16x16bf16_1k(PAhi, bhi, c, 0, 0, 0);
            c = __builtin_amdgcn_mfma_f32_16x16x16bf16_1k(PAhi, blo, c, 0, 0, 0);
            c = __builtin_amdgcn_mfma_f32_16x16x16bf16_1k(PAlo, bhi, c, 0, 0, 0);
            float* sp = Smix + m * SRAW_SLAB + l16 * SRAW_PITCH + qq * 4;
            *(float2*)sp       = make_float2(c[0], c[1]);
            *(float2*)(sp + 2) = make_float2(c[2], c[3]);
        }
    };

    // body(t): stage V(t); prefetch(t+2); mixMFMA(t); B_mid; softmax+PV(t);
    // qkt(t+1)->other Sraw; rescale; B_end.
    auto body = [&](const float* sb, float* sbo, bf16x8 (&vstage)[4], bf16x8 (&kqk)[2][2],
                    bf16x8 (&kld)[2][2], bf16x8 (&vld)[4], int tnext) {
        // 1. stage V(t) into per-wave slab
        #pragma unroll
        for (int i = 0; i < 4; ++i) {
            bf16x4 wlo = { vstage[i][0], vstage[i][1], vstage[i][2], vstage[i][3] };
            bf16x4 whi = { vstage[i][4], vstage[i][5], vstage[i][6], vstage[i][7] };
            *(bf16x4*)&Vslab[w][vwoff[i]]     = wlo;
            *(bf16x4*)&Vslab[w][vwoff[i] + 4] = whi;
        }
        // 2. prefetch tile tnext (global -> regs, in flight across barriers)
        {
            const int mn = tnext * 16;
            #pragma unroll
            for (int hh = 0; hh < 2; ++hh)
                #pragma unroll
                for (int kc = 0; kc < 2; ++kc)
                    kld[hh][kc] = *(const bf16x8*)(kh + ((hb + 2 * w + hh) * L_ + mn + l16) * HD_ + kc * 32 + qq * 8);
            #pragma unroll
            for (int i = 0; i < 4; ++i)
                vld[i] = *(const bf16x8*)(vht + ((hb + 2 * w + vgi_[i]) * HD_ + vd_[i]) * (size_t)L_ + mn + vc * 8);
        }
        // 3. mix via MFMA -> Smix
        mixmfma(sb);
        block_sync();   // B_mid: Smix visible to all waves
        // 4. softmax inputs: lane (l16, qq) reads smix[m=qq*4+j][l16][g] for g=2w,2w+1
        float sx0[4], sx1[4];
        #pragma unroll
        for (int j = 0; j < 4; ++j) {
            const float* mp = Smix + (qq * 4 + j) * SRAW_SLAB + l16 * SRAW_PITCH;
            sx0[j] = mp[2 * w];
            sx1[j] = mp[2 * w + 1];
        }
        // 5. deferred-max softmax: pf vs m_old; reduces off the PV critical path
        float e00 = __expf(sx0[0] - mrun0), e01 = __expf(sx0[1] - mrun0);
        float e02 = __expf(sx0[2] - mrun0), e03 = __expf(sx0[3] - mrun0);
        float e10 = __expf(sx1[0] - mrun1), e11 = __expf(sx1[1] - mrun1);
        float e12 = __expf(sx1[2] - mrun1), e13 = __expf(sx1[3] - mrun1);
        bf16x4 pf0 = { f2bf(e00), f2bf(e01), f2bf(e02), f2bf(e03) };
        bf16x4 pf1 = { f2bf(e10), f2bf(e11), f2bf(e12), f2bf(e13) };
        float t0 = fmaxf(fmaxf(sx0[0], sx0[1]), fmaxf(sx0[2], sx0[3]));
        float t1 = fmaxf(fmaxf(sx1[0], sx1[1]), fmaxf(sx1[2], sx1[3]));
        t0 = fmaxf(t0, __shfl_xor(t0, 16)); t0 = fmaxf(t0, __shfl_xor(t0, 32));
        t1 = fmaxf(t1, __shfl_xor(t1, 16)); t1 = fmaxf(t1, __shfl_xor(t1, 32));
        float ps0 = e00 + e01 + e02 + e03, ps1 = e10 + e11 + e12 + e13;
        ps0 += __shfl_xor(ps0, 16); ps0 += __shfl_xor(ps0, 32);
        ps1 += __shfl_xor(ps1, 16); ps1 += __shfl_xor(ps1, 32);
        // 6. PV: A = V^T rows d from slab (b64), B = pf.  D[d][l], col=l16.
        #pragma unroll
        for (int i = 0; i < 2; ++i) {
            bf16x4 pf = i ? pf1 : pf0;
            #pragma unroll
            for (int dt = 0; dt < 4; ++dt) {
                bf16x4 afr = *(const bf16x4*)&Vslab[w][i * (64 * VS_PITCH) + (dt * 16 + l16) * VS_PITCH + qq * 4];
                acc[i][dt] = __builtin_amdgcn_mfma_f32_16x16x16bf16_1k(afr, pf, acc[i][dt], 0, 0, 0);
            }
        }
        // 7. QK^T(t+1) -> other Sraw buffer
        qkt(kqk, sbo);
        // 8. end-of-body rescale to new running max
        float mnew0 = fmaxf(mrun0, t0), mnew1 = fmaxf(mrun1, t1);
        float corr0 = __expf(mrun0 - mnew0), corr1 = __expf(mrun1 - mnew1);
        srun0 = (srun0 + ps0) * corr0; srun1 = (srun1 + ps1) * corr1;
        acc[0][0] *= corr0; acc[0][1] *= corr0; acc[0][2] *= corr0; acc[0][3] *= corr0;
        acc[1][0] *= corr1; acc[1][1] *= corr1; acc[1][2] *= corr1; acc[1][3] *= corr1;
        mrun0 = mnew0; mrun1 = mnew1;
        block_sync();   // B_end: Sraw_other + Smix WAR resolved; prefetches in flight
    };

    for (int itp = 0; itp < 64; ++itp) {
        const int t0 = 2 * itp;
        body(Sraw0, Sraw1, vA, kB, kA, vA, (t0 + 2) & 127);   // even tile t0
        body(Sraw1, Sraw0, vB, kA, kB, vB, (t0 + 3) & 127);   // odd tile t0+1
    }

    // epilogue: D[d][l] -> out[b][l][g*64 + d]
    float inv0 = 1.f / srun0, inv1 = 1.f / srun1;
    #pragma unroll
    for (int i = 0; i < 2; ++i) {
        float inv = i ? inv1 : inv0;
        #pragma unroll
        for (int dt = 0; dt < 4; ++dt) {
            f32x4 a = acc[i][dt];
            bf16x4 ov = { f2bf(a[0] * inv), f2bf(a[1] * inv), f2bf(a[2] * inv), f2bf(a[3] * inv) };
            *(bf16x4*)(attn_out + ((size_t)(b * L_ + l0 + l16)) * D_ + (2 * w + i) * 64 + dt * 16 + qq * 4) = ov;
        }
    }
}

// ---------------------------------------------------------------------------
// Kernel 3: output projection (attn bf16 @ Wo^T + bo) -> f32, MFMA.
// ---------------------------------------------------------------------------
__global__ __launch_bounds__(256) void out_mfma(
    const short* __restrict__ attn, const float* __restrict__ Wo,
    const float* __restrict__ bo, float* __restrict__ out)
{
    __shared__ short Ws[128][40];
    __shared__ short Xs[128][40];

    const int tid = threadIdx.x;
    const int w = tid >> 6, lane = tid & 63;
    const int l16 = lane & 15, qq = lane >> 4;
    const int m0 = blockIdx.x * 128;
    const int n0 = blockIdx.y * 128;
    const int ar0 = 64 * (w & 1);
    const int br0 = 64 * (w >> 1);

    f32x4 acc[4][4] = {};

    for (int k0 = 0; k0 < D_; k0 += 32) {
        #pragma unroll
        for (int i = 0; i < 4; ++i) {
            int fidx = i * 256 + tid;
            int r = fidx >> 3, c = fidx & 7;
            float4 wv4 = *(const float4*)(Wo + (size_t)(n0 + r) * D_ + k0 + c * 4);
            bf16x4 wb = { f2bf(wv4.x), f2bf(wv4.y), f2bf(wv4.z), f2bf(wv4.w) };
            *(bf16x4*)&Ws[r][c * 4] = wb;
        }
        #pragma unroll
        for (int i = 0; i < 2; ++i) {
            int cidx = i * 256 + tid;
            int r = cidx >> 2, c = cidx & 3;
            bf16x8 xv = *(const bf16x8*)(attn + (size_t)(m0 + r) * D_ + k0 + c * 8);
            *(bf16x8*)&Xs[r][c * 8] = xv;
        }
        __syncthreads();
        bf16x8 af[4], bfv[4];
        #pragma unroll
        for (int i = 0; i < 4; ++i) {
            af[i]  = *(const bf16x8*)&Ws[ar0 + 16 * i + l16][qq * 8];
            bfv[i] = *(const bf16x8*)&Xs[br0 + 16 * i + l16][qq * 8];
        }
        #pragma unroll
        for (int i = 0; i < 4; ++i)
            #pragma unroll
            for (int j = 0; j < 4; ++j)
                acc[i][j] = __builtin_amdgcn_mfma_f32_16x16x32_bf16(af[i], bfv[j], acc[i][j], 0, 0, 0);
        __syncthreads();
    }

    #pragma unroll
    for (int i = 0; i < 4; ++i) {
        int nb = n0 + ar0 + 16 * i + qq * 4;
        float4 b4 = *(const float4*)(bo + nb);
        #pragma unroll
        for (int j = 0; j < 4; ++j) {
            int m = m0 + br0 + 16 * j + l16;
            f32x4 c = acc[i][j];
            float4 ov = make_float4(c[0] + b4.x, c[1] + b4.y, c[2] + b4.z, c[3] + b4.w);
            *(float4*)&out[(size_t)m * D_ + nb] = ov;
        }
    }
}

// ---------------------------------------------------------------------------
extern "C" void kernel_launch(void* const* d_in, const int* in_sizes, int n_in,
                              void* d_out, int out_size, void* d_ws, size_t ws_size,
                              hipStream_t stream) {
    const float* q  = (const float*)d_in[0];
    const float* k  = (const float*)d_in[1];
    const float* v  = (const float*)d_in[2];
    const float* Wq = (const float*)d_in[3];
    const float* bq = (const float*)d_in[4];
    const float* Wk = (const float*)d_in[5];
    const float* bk = (const float*)d_in[6];
    const float* Wv = (const float*)d_in[7];
    const float* bv = (const float*)d_in[8];
    const float* Wo = (const float*)d_in[9];
    const float* bo = (const float*)d_in[10];
    const float* P  = (const float*)d_in[11];
    float* out = (float*)d_out;

    // ws: qh 8MB | qlo 8MB | kh 8MB | vht 8MB | attn 8MB (all bf16/short)
    char* ws = (char*)d_ws;
    short* qh   = (short*)(ws);
    short* qlo  = (short*)(ws + (size_t)8 * 1024 * 1024);
    short* kh   = (short*)(ws + (size_t)16 * 1024 * 1024);
    short* vht  = (short*)(ws + (size_t)24 * 1024 * 1024);
    short* attn = (short*)(ws + (size_t)32 * 1024 * 1024);

    proj_mfma<<<dim3(M_ / 128, D_ / 128, 3), 256, 0, stream>>>(
        q, k, v, Wq, bq, Wk, bk, Wv, bv, qh, qlo, kh, vht);
    attn_mfma<<<dim3(256), 512, 0, stream>>>(qh, qlo, kh, vht, P, attn);
    out_mfma<<<dim3(M_ / 128, D_ / 128), 256, 0, stream>>>(attn, Wo, bo, out);
}